// Round 4
// baseline (292.540 us; speedup 1.0000x reference)
//
#include <hip/hip_runtime.h>
#include <hip/hip_bf16.h>
#include <cstdint>

// Problem constants
#define Tn 12
#define Nn 512
#define WIN 12
#define DFT 256
#define Pn 16
#define Mrows 24576

typedef unsigned long long u64;
typedef __attribute__((ext_vector_type(8))) short short8;
typedef __attribute__((ext_vector_type(4))) float f32x4;
typedef __attribute__((address_space(1))) const void* gas1;
typedef __attribute__((address_space(3))) void* las3;

static __device__ __forceinline__ void gld16(const void* g, void* l) {
  __builtin_amdgcn_global_load_lds((gas1)g, (las3)l, 16, 0, 0);
}
static __device__ __forceinline__ short f2bf(float x) {
  __hip_bfloat16 h = __float2bfloat16(x);
  return *reinterpret_cast<short*>(&h);
}
static __device__ __forceinline__ float bf2f(short s) {
  __hip_bfloat16 h;
  *reinterpret_cast<short*>(&h) = s;
  return __bfloat162float(h);
}
static __device__ __forceinline__ f32x4 mfma16(short8 a, short8 b, f32x4 c) {
  return __builtin_amdgcn_mfma_f32_16x16x32_bf16(a, b, c, 0, 0, 0);
}

// ---- cast + concat + fused scalar: one wave per row ----
__global__ __launch_bounds__(256) void cast_concat_sc(
    const float* __restrict__ X, const float* __restrict__ STE,
    const float* __restrict__ Ws, short* __restrict__ Abf,
    float* __restrict__ scalar) {
  const int lane = threadIdx.x & 63, w = threadIdx.x >> 6;
  const int m = blockIdx.x * 4 + w;
  const int c8 = lane * 8;
  const float4 x0 = *reinterpret_cast<const float4*>(&X[(size_t)m * 512 + c8]);
  const float4 x1 = *reinterpret_cast<const float4*>(&X[(size_t)m * 512 + c8 + 4]);
  short8 xo;
  xo[0]=f2bf(x0.x); xo[1]=f2bf(x0.y); xo[2]=f2bf(x0.z); xo[3]=f2bf(x0.w);
  xo[4]=f2bf(x1.x); xo[5]=f2bf(x1.y); xo[6]=f2bf(x1.z); xo[7]=f2bf(x1.w);
  *reinterpret_cast<short8*>(&Abf[(size_t)m * 1024 + c8]) = xo;
  const float4 s0 = *reinterpret_cast<const float4*>(&STE[(size_t)m * 512 + c8]);
  const float4 s1 = *reinterpret_cast<const float4*>(&STE[(size_t)m * 512 + c8 + 4]);
  short8 so;
  so[0]=f2bf(s0.x); so[1]=f2bf(s0.y); so[2]=f2bf(s0.z); so[3]=f2bf(s0.w);
  so[4]=f2bf(s1.x); so[5]=f2bf(s1.y); so[6]=f2bf(s1.z); so[7]=f2bf(s1.w);
  *reinterpret_cast<short8*>(&Abf[(size_t)m * 1024 + 512 + c8]) = so;
  // fused scalar = X row . W_scalar (f32)
  const float4 w0 = *reinterpret_cast<const float4*>(&Ws[c8]);
  const float4 w1 = *reinterpret_cast<const float4*>(&Ws[c8 + 4]);
  float d = x0.x*w0.x + x0.y*w0.y + x0.z*w0.z + x0.w*w0.w
          + x1.x*w1.x + x1.y*w1.y + x1.z*w1.z + x1.w*w1.w;
#pragma unroll
  for (int off = 32; off; off >>= 1) d += __shfl_xor(d, off);
  if (lane == 0) scalar[m] = d;
}

// ---- stacked transposed weights: Wt3[n][k], n 0..1535 ----
__global__ __launch_bounds__(256) void prep_wqkv(
    const float* __restrict__ Wq, const float* __restrict__ Wk,
    const float* __restrict__ Wv, short* __restrict__ Wt3) {
  const int i = blockIdx.x * 256 + threadIdx.x;
  const int n = i >> 10, kk = i & 1023;
  const float* W = (n < 512) ? Wq : ((n < 1024) ? Wk : Wv);
  Wt3[(size_t)n * 1024 + kk] = f2bf(W[(size_t)kk * 512 + (n & 511)]);
}

__global__ __launch_bounds__(256) void cast_wo(
    const float* __restrict__ W, short* __restrict__ Wt) {
  const int i = blockIdx.x * 256 + threadIdx.x;
  const int n = i >> 9, kk = i & 511;
  Wt[(size_t)n * 512 + kk] = f2bf(W[(size_t)kk * 512 + n]);
}

__global__ __launch_bounds__(256) void bias_cat(
    const float* __restrict__ bq, const float* __restrict__ bk,
    const float* __restrict__ bv, float* __restrict__ bqkv) {
  const int i = blockIdx.x * 256 + threadIdx.x;
  bqkv[i] = (i < 512) ? bq[i] : ((i < 1024) ? bk[i - 512] : bv[i - 1024]);
}

// ---- pack masks to bitwords ----
__global__ __launch_bounds__(256) void pack_mask(
    const int* __restrict__ geo, const int* __restrict__ sem,
    u64* __restrict__ gbits, u64* __restrict__ sbits) {
  const int lane = threadIdx.x & 63;
  const int unit = blockIdx.x * 4 + (threadIdx.x >> 6);
  const int n = unit >> 3, seg = unit & 7;
  const int* __restrict__ src = blockIdx.y ? sem : geo;
  u64* __restrict__ dst = blockIdx.y ? sbits : gbits;
  const int mv = src[(size_t)n * 512 + seg * 64 + lane];
  const u64 word = __ballot(mv != 0);
  if (lane == 0) dst[(size_t)n * 8 + seg] = word;
}

// =================== 256x256 8-phase QKV GEMM ===================
// A [24576 x 1024] bf16, Wt [1536 x 1024] bf16.
// cols < 1024 -> Cm (q|k, relu bf16); cols >= 1024 -> vT [512][24576] transposed.
// Schedule: T2 swizzle + T3/T4 8-phase counted vmcnt(6) + T5 setprio.
// LDS units: A-u0 = rows{0-63,128-191}, A-u1 = rows{64-127,192-255} (16KB each);
// B-u0 = cols with (c&63)<32, B-u1 = rest. Stage unit = 2 gld16/thread.
#define STAGE_A(DB, U, T) { \
  const size_t so_ = (size_t)(row0 + (U)*64 + aur) * 1024 + (T)*64 + asg; \
  gld16(&A[so_], &Asl[DB][(U)*8192 + w*512]); \
  gld16(&A[so_ + (size_t)128*1024], &Asl[DB][(U)*8192 + 4096 + w*512]); }

#define STAGE_B(DB, U, T) { \
  const int nc_ = col0 + (U)*32 + (aur & 31) + ((aur >> 5) << 6); \
  const size_t so_ = (size_t)nc_ * 1024 + (T)*64 + asg; \
  gld16(&Wt[so_], &Bsl[DB][(U)*8192 + w*512]); \
  gld16(&Wt[so_ + (size_t)128*1024], &Bsl[DB][(U)*8192 + 4096 + w*512]); }

#define LOAD_A(DB, MH) { \
  _Pragma("unroll") for (int ms = 0; ms < 4; ++ms) { \
    const int ao_ = (MH)*8192 + (wm*64 + ms*16 + lc) * 64; \
    afr[ms][0] = *reinterpret_cast<const short8*>(&Asl[DB][ao_ + ksw0]); \
    afr[ms][1] = *reinterpret_cast<const short8*>(&Asl[DB][ao_ + ksw1]); } }

#define LOAD_B(DB, NH) { \
  _Pragma("unroll") for (int ns = 0; ns < 2; ++ns) { \
    const int bo_ = (NH)*8192 + (wn*32 + ns*16 + lc) * 64; \
    bfr[NH][ns][0] = *reinterpret_cast<const short8*>(&Bsl[DB][bo_ + ksw0]); \
    bfr[NH][ns][1] = *reinterpret_cast<const short8*>(&Bsl[DB][bo_ + ksw1]); } }

#define MFMAQ(MH, NH) { \
  _Pragma("unroll") for (int ms = 0; ms < 4; ++ms) \
    _Pragma("unroll") for (int ns = 0; ns < 2; ++ns) { \
      acc[(MH)*4+ms][(NH)*2+ns] = mfma16(afr[ms][0], bfr[NH][ns][0], acc[(MH)*4+ms][(NH)*2+ns]); \
      acc[(MH)*4+ms][(NH)*2+ns] = mfma16(afr[ms][1], bfr[NH][ns][1], acc[(MH)*4+ms][(NH)*2+ns]); } }

#define FENCE asm volatile("" ::: "memory")
#define BAR1 { FENCE; __builtin_amdgcn_s_barrier(); \
  asm volatile("s_waitcnt lgkmcnt(0)" ::: "memory"); \
  __builtin_amdgcn_sched_barrier(0); __builtin_amdgcn_s_setprio(1); }
#define ENDP0 { __builtin_amdgcn_s_setprio(0); FENCE; __builtin_amdgcn_s_barrier(); }
#define ENDPV { __builtin_amdgcn_s_setprio(0); \
  asm volatile("s_waitcnt vmcnt(6)" ::: "memory"); FENCE; __builtin_amdgcn_s_barrier(); }

__global__ __launch_bounds__(512, 2) void gemm256(
    const short* __restrict__ A, const short* __restrict__ Wt,
    const float* __restrict__ bias, short* __restrict__ Cm,
    short* __restrict__ vT) {
  __shared__ alignas(16) short Asl[2][16384];
  __shared__ alignas(16) short Bsl[2][16384];
  const int tid = threadIdx.x, lane = tid & 63, w = tid >> 6;
  const int wm = w >> 2, wn = w & 3;
  const int lg = lane >> 4, lc = lane & 15;
  const int L = blockIdx.x;                    // 576 blocks, XCD-bijective
  const int rp = (L & 7) * 12 + (L >> 3) / 6;  // row panel 0..95
  const int cb = (L >> 3) % 6;                 // col panel 0..5
  const int row0 = rp * 256, col0 = cb * 256;
  const int aur = w * 8 + (lane >> 3);
  const int asg = ((lane & 7) ^ (aur & 7)) * 8;
  const int ksw0 = (lg ^ (lc & 7)) * 8;
  const int ksw1 = ((4 + lg) ^ (lc & 7)) * 8;

  f32x4 acc[8][4];
#pragma unroll
  for (int i = 0; i < 8; ++i)
#pragma unroll
    for (int j = 0; j < 4; ++j) acc[i][j] = (f32x4){0.f, 0.f, 0.f, 0.f};
  short8 afr[4][2];
  short8 bfr[2][2][2];

  // prologue: tile0 fully + tile1 first 3 units -> 6 loads in flight after wait
  STAGE_A(0, 0, 0); STAGE_B(0, 0, 0); STAGE_B(0, 1, 0); STAGE_A(0, 1, 0);
  STAGE_A(1, 0, 1); STAGE_B(1, 0, 1); STAGE_B(1, 1, 1);
  asm volatile("s_waitcnt vmcnt(6)" ::: "memory");
  FENCE;
  __builtin_amdgcn_s_barrier();

#pragma unroll 1
  for (int i = 0; i < 8; ++i) {                // 16 K-tiles, 2 per iteration
    const int t2 = (i < 7) ? 2 * i + 2 : 15;   // clamped prefetch targets
    const int t3 = (i < 7) ? 2 * i + 3 : 15;
    // p1: compute tile 2i (buf0) quadrant (0,0); stage A-u1(2i+1)->buf1
    LOAD_A(0, 0); LOAD_B(0, 0);
    STAGE_A(1, 1, 2 * i + 1);
    BAR1; MFMAQ(0, 0); ENDP0;
    // p2: quadrant (0,1); stage A-u0(2i+2)->buf0 (dead since p1)
    LOAD_B(0, 1);
    STAGE_A(0, 0, t2);
    BAR1; MFMAQ(0, 1); ENDP0;
    // p3: quadrant (1,0); stage B-u0(2i+2)->buf0 (dead since p1)
    LOAD_A(0, 1);
    STAGE_B(0, 0, t2);
    BAR1; MFMAQ(1, 0); ENDP0;
    // p4: quadrant (1,1); stage B-u1(2i+2)->buf0 (dead since p2); counted wait
    STAGE_B(0, 1, t2);
    BAR1; MFMAQ(1, 1); ENDPV;
    // p5: compute tile 2i+1 (buf1) quadrant (0,0); stage A-u1(2i+2)->buf0 (dead p3)
    LOAD_A(1, 0); LOAD_B(1, 0);
    STAGE_A(0, 1, t2);
    BAR1; MFMAQ(0, 0); ENDP0;
    // p6: quadrant (0,1); stage A-u0(2i+3)->buf1 (dead since p5)
    LOAD_B(1, 1);
    STAGE_A(1, 0, t3);
    BAR1; MFMAQ(0, 1); ENDP0;
    // p7: quadrant (1,0); stage B-u0(2i+3)->buf1 (dead since p5)
    LOAD_A(1, 1);
    STAGE_B(1, 0, t3);
    BAR1; MFMAQ(1, 0); ENDP0;
    // p8: quadrant (1,1); stage B-u1(2i+3)->buf1 (dead since p6); counted wait
    STAGE_B(1, 1, t3);
    BAR1; MFMAQ(1, 1); ENDPV;
  }

  // epilogue
  if (col0 < 1024) {
#pragma unroll
    for (int mf = 0; mf < 8; ++mf) {
      const int row = row0 + wm * 128 + (mf >> 2) * 64 + (mf & 3) * 16 + lg * 4;
#pragma unroll
      for (int nf = 0; nf < 4; ++nf) {
        const int colg = col0 + wn * 64 + (nf >> 1) * 32 + (nf & 1) * 16 + lc;
        const float bv = bias[colg];
#pragma unroll
        for (int r = 0; r < 4; ++r) {
          float vv = acc[mf][nf][r] + bv;
          Cm[(size_t)(row + r) * 1024 + colg] = f2bf(vv > 0.f ? vv : 0.f);
        }
      }
    }
  } else {
#pragma unroll
    for (int mf = 0; mf < 8; ++mf) {
      const int row = row0 + wm * 128 + (mf >> 2) * 64 + (mf & 3) * 16 + lg * 4;
#pragma unroll
      for (int nf = 0; nf < 4; ++nf) {
        const int colg = col0 + wn * 64 + (nf >> 1) * 32 + (nf & 1) * 16 + lc;
        const float bv = bias[colg];
        short4 t4;
        float v0 = acc[mf][nf][0] + bv; t4.x = f2bf(v0 > 0.f ? v0 : 0.f);
        float v1 = acc[mf][nf][1] + bv; t4.y = f2bf(v1 > 0.f ? v1 : 0.f);
        float v2 = acc[mf][nf][2] + bv; t4.z = f2bf(v2 > 0.f ? v2 : 0.f);
        float v3 = acc[mf][nf][3] + bv; t4.w = f2bf(v3 > 0.f ? v3 : 0.f);
        *reinterpret_cast<short4*>(&vT[(size_t)(colg - 1024) * Mrows + row]) = t4;
      }
    }
  }
}

// ---- 128x128 MFMA GEMM (kept for output FC, f32 out) ----
__global__ __launch_bounds__(256) void gemm128o(
    const short* __restrict__ A,
    const short* __restrict__ Wt, const float* __restrict__ bias,
    float* __restrict__ Cf) {
  __shared__ alignas(16) short As[128 * 64];
  __shared__ alignas(16) short Bs[128 * 64];
  const int tid = threadIdx.x, lane = tid & 63, w = tid >> 6;
  const int wm = w >> 1, wn = w & 1, lg = lane >> 4, lc = lane & 15;
  const int L = blockIdx.x;
  const int x = L & 7, j = L >> 3;
  const int rp = x * 24 + j / 4, cb = j - (j / 4) * 4;
  const int row0 = rp * 128, col0 = cb * 128;
  f32x4 acc[4][4];
#pragma unroll
  for (int i = 0; i < 4; ++i)
#pragma unroll
    for (int jj = 0; jj < 4; ++jj) acc[i][jj] = (f32x4){0.f, 0.f, 0.f, 0.f};

  for (int k0 = 0; k0 < 512; k0 += 64) {
    __syncthreads();
#pragma unroll
    for (int c = 0; c < 4; ++c) {
      const int slot0 = w * 256 + c * 64;
      const int slot = slot0 + lane;
      const int r = slot >> 3, gs = slot & 7, g = gs ^ (r & 7);
      gld16(&A[(size_t)(row0 + r) * 512 + k0 + g * 8], &As[slot0 * 8]);
      gld16(&Wt[(size_t)(col0 + r) * 512 + k0 + g * 8], &Bs[slot0 * 8]);
    }
    __syncthreads();
#pragma unroll
    for (int kh = 0; kh < 2; ++kh) {
      short8 b[4];
#pragma unroll
      for (int ns = 0; ns < 4; ++ns) {
        const int rb = wn * 64 + ns * 16 + lc;
        b[ns] = *reinterpret_cast<const short8*>(
            &Bs[(rb * 8 + ((kh * 4 + lg) ^ (rb & 7))) * 8]);
      }
#pragma unroll
      for (int ms = 0; ms < 4; ++ms) {
        const int ra = wm * 64 + ms * 16 + lc;
        const short8 a = *reinterpret_cast<const short8*>(
            &As[(ra * 8 + ((kh * 4 + lg) ^ (ra & 7))) * 8]);
#pragma unroll
        for (int ns = 0; ns < 4; ++ns) acc[ms][ns] = mfma16(a, b[ns], acc[ms][ns]);
      }
    }
  }
#pragma unroll
  for (int ms = 0; ms < 4; ++ms) {
    const int rowb = row0 + wm * 64 + ms * 16 + lg * 4;
#pragma unroll
    for (int ns = 0; ns < 4; ++ns) {
      const int colg = col0 + wn * 64 + ns * 16 + lc;
      const float bv = bias[colg];
#pragma unroll
      for (int r = 0; r < 4; ++r) {
        float vv = acc[ms][ns][r] + bv;
        Cf[(size_t)(rowb + r) * 512 + colg] = vv > 0.f ? vv : 0.f;
      }
    }
  }
}

// ---- mem/val = pattern_keys @ W_pm/W_pv ----
__global__ __launch_bounds__(256) void memval_kernel(
    const float* __restrict__ PK, const float* __restrict__ Wpm,
    const float* __restrict__ Wpv, float* __restrict__ mem,
    float* __restrict__ val) {
  const int p = blockIdx.x, f = threadIdx.x;
  float m = 0.f, v = 0.f;
#pragma unroll
  for (int i = 0; i < WIN; ++i) {
    const float pk = PK[p * WIN + i];
    m += pk * Wpm[i * DFT + f];
    v += pk * Wpv[i * DFT + f];
  }
  mem[p * DFT + f] = m;
  val[p * DFT + f] = v;
}

// ---- DFT branch: 8 rows/block, adds into q channels [0,256) ----
__global__ __launch_bounds__(256) void dft_kernel(
    const float* __restrict__ scalar, const float* __restrict__ Wwq,
    const float* __restrict__ mem, const float* __restrict__ val,
    short* __restrict__ q) {
  const int mrow0 = blockIdx.x * 8;
  const int bt = mrow0 >> 9;
  const int nb = mrow0 & 511;
  const int t = bt % Tn;
  const int tid = threadIdx.x;
  __shared__ float meml[16][256];
  __shared__ float vall[16][256];
  __shared__ float wl[8][12];
  __shared__ float qd[256];
  __shared__ float psum[16][17];
  __shared__ float al[16];
  for (int i = tid; i < 4096; i += 256) {
    meml[i >> 8][i & 255] = mem[i];
    vall[i >> 8][i & 255] = val[i];
  }
  if (tid < 96) {
    const int r = tid / 12, i = tid % 12;
    const int ti = t + i - (WIN - 1);
    wl[r][i] = (ti >= 0) ? scalar[(size_t)(bt + i - (WIN - 1)) * Nn + nb + r] : 0.f;
  }
  __syncthreads();
  for (int r = 0; r < 8; ++r) {
    float qf = 0.f;
#pragma unroll
    for (int i = 0; i < WIN; ++i) qf += wl[r][i] * Wwq[i * DFT + tid];
    qd[tid] = qf;
    __syncthreads();
    {
      const int p = tid >> 4, seg = tid & 15;
      float part = 0.f;
#pragma unroll
      for (int jj = 0; jj < 16; ++jj)
        part += qd[seg * 16 + jj] * meml[p][seg * 16 + jj];
      psum[p][seg] = part;
    }
    __syncthreads();
    if (tid < 16) {
      float s = 0.f;
#pragma unroll
      for (int jj = 0; jj < 16; ++jj) s += psum[tid][jj];
      s *= 0.0625f;
      float mx = s;
#pragma unroll
      for (int off = 8; off; off >>= 1) mx = fmaxf(mx, __shfl_xor(mx, off, 16));
      const float e = __expf(s - mx);
      float sum = e;
#pragma unroll
      for (int off = 8; off; off >>= 1) sum += __shfl_xor(sum, off, 16);
      al[tid] = e / sum;
    }
    __syncthreads();
    float ov = 0.f;
#pragma unroll
    for (int p2 = 0; p2 < Pn; ++p2) ov += al[p2] * vall[p2][tid];
    const size_t qi = (size_t)(mrow0 + r) * 1024 + tid;
    q[qi] = f2bf(bf2f(q[qi]) + ov);
    __syncthreads();
  }
}

// ---- MFMA flash attention (XCD-grouped, gld_lds staging, T5 setprio) ----
__global__ __launch_bounds__(256) void attn2(
    const short* __restrict__ Cm, const short* __restrict__ vT,
    const u64* __restrict__ gbits, const u64* __restrict__ sbits,
    short* __restrict__ merged) {
  const int L = blockIdx.x;            // 0..3071
  const int x = L & 7, jj = L >> 3;
  const int g = x * 48 + (jj >> 3);    // same (head,bt) -> same XCD
  const int qt = jj & 7;
  const int head = g & 7, bt = g >> 3;
  const u64* __restrict__ bits = (head < 4) ? gbits : sbits;
  const int tid = threadIdx.x, lane = tid & 63, w = tid >> 6;
  const int lg = lane >> 4, qc = lane & 15;
  const size_t rowbase = (size_t)bt * 512;
  const int n0 = qt * 64;
  const int qcol = head * 64, kcol = 512 + head * 64, vrow0 = head * 64;

  __shared__ alignas(16) short Klds[64 * 64];
  __shared__ alignas(16) short Vlds[64 * 64];
  __shared__ alignas(16) short Plds[4][16][72];
  __shared__ u64 mlds[64][8];

  for (int i = tid; i < 512; i += 256)
    mlds[i >> 3][i & 7] = bits[(size_t)(n0 + (i >> 3)) * 8 + (i & 7)];

  const int qrow = n0 + w * 16 + qc;
  const short8 qf0 = *reinterpret_cast<const short8*>(
      &Cm[(rowbase + qrow) * 1024 + qcol + lg * 8]);
  const short8 qf1 = *reinterpret_cast<const short8*>(
      &Cm[(rowbase + qrow) * 1024 + qcol + 32 + lg * 8]);

  float m_run = -1e30f, l_run = 0.f;
  f32x4 o[4];
#pragma unroll
  for (int i = 0; i < 4; ++i) o[i] = (f32x4){0.f, 0.f, 0.f, 0.f};

  for (int ch = 0; ch < 8; ++ch) {
    __syncthreads();
#pragma unroll
    for (int c = 0; c < 2; ++c) {
      const int slot0 = (w * 2 + c) * 64;
      const int slot = slot0 + lane;
      const int r = slot >> 3, gs = slot & 7, gg = gs ^ (r & 7);
      gld16(&Cm[(rowbase + ch * 64 + r) * 1024 + kcol + gg * 8], &Klds[slot0 * 8]);
      gld16(&vT[(size_t)(vrow0 + r) * Mrows + rowbase + ch * 64 + gg * 8],
            &Vlds[slot0 * 8]);
    }
    __syncthreads();

    const u64 mword = mlds[w * 16 + qc][ch];
    float p[4][4];
    float cm = -1e30f;
#pragma unroll
    for (int s = 0; s < 4; ++s) {
      f32x4 sa = (f32x4){0.f, 0.f, 0.f, 0.f};
      const int rk = s * 16 + qc;
      const short8 a0 = *reinterpret_cast<const short8*>(
          &Klds[(rk * 8 + (lg ^ (rk & 7))) * 8]);
      const short8 a1 = *reinterpret_cast<const short8*>(
          &Klds[(rk * 8 + ((4 + lg) ^ (rk & 7))) * 8]);
      __builtin_amdgcn_s_setprio(1);
      sa = mfma16(a0, qf0, sa);
      sa = mfma16(a1, qf1, sa);
      __builtin_amdgcn_s_setprio(0);
#pragma unroll
      for (int r = 0; r < 4; ++r) {
        const int kb = s * 16 + lg * 4 + r;
        const bool bit = (mword >> kb) & 1ull;
        const float sv = bit ? sa[r] * 0.125f : -1e30f;
        p[s][r] = sv;
        cm = fmaxf(cm, sv);
      }
    }
    cm = fmaxf(cm, __shfl_xor(cm, 16));
    cm = fmaxf(cm, __shfl_xor(cm, 32));
    if (__any(cm > m_run)) {
      const float m_new = fmaxf(m_run, cm);
      const float alpha = __expf(m_run - m_new);
      l_run *= alpha;
#pragma unroll
      for (int i = 0; i < 4; ++i) o[i] *= alpha;
      m_run = m_new;
    }
    float csum = 0.f;
#pragma unroll
    for (int s = 0; s < 4; ++s) {
      short4 p4;
      float pv0 = (p[s][0] > -1e29f) ? __expf(p[s][0] - m_run) : 0.f;
      float pv1 = (p[s][1] > -1e29f) ? __expf(p[s][1] - m_run) : 0.f;
      float pv2 = (p[s][2] > -1e29f) ? __expf(p[s][2] - m_run) : 0.f;
      float pv3 = (p[s][3] > -1e29f) ? __expf(p[s][3] - m_run) : 0.f;
      csum += pv0 + pv1 + pv2 + pv3;
      p4.x = f2bf(pv0); p4.y = f2bf(pv1); p4.z = f2bf(pv2); p4.w = f2bf(pv3);
      *reinterpret_cast<short4*>(&Plds[w][qc][s * 16 + lg * 4]) = p4;
    }
    csum += __shfl_xor(csum, 16);
    csum += __shfl_xor(csum, 32);
    l_run += csum;

#pragma unroll
    for (int kh = 0; kh < 2; ++kh) {
      const short8 pb = *reinterpret_cast<const short8*>(
          &Plds[w][qc][kh * 32 + lg * 8]);
      __builtin_amdgcn_s_setprio(1);
#pragma unroll
      for (int ds = 0; ds < 4; ++ds) {
        const int rd = ds * 16 + qc;
        const short8 va = *reinterpret_cast<const short8*>(
            &Vlds[(rd * 8 + ((kh * 4 + lg) ^ (rd & 7))) * 8]);
        o[ds] = mfma16(va, pb, o[ds]);
      }
      __builtin_amdgcn_s_setprio(0);
    }
  }
  const float inv = l_run > 0.f ? 1.f / l_run : 0.f;
#pragma unroll
  for (int ds = 0; ds < 4; ++ds) {
    short4 t4;
    t4.x = f2bf(o[ds][0] * inv);
    t4.y = f2bf(o[ds][1] * inv);
    t4.z = f2bf(o[ds][2] * inv);
    t4.w = f2bf(o[ds][3] * inv);
    *reinterpret_cast<short4*>(
        &merged[(rowbase + qrow) * 512 + head * 64 + ds * 16 + lg * 4]) = t4;
  }
}

// ---------------- launch ----------------
extern "C" void kernel_launch(void* const* d_in, const int* in_sizes, int n_in,
                              void* d_out, int out_size, void* d_ws, size_t ws_size,
                              hipStream_t stream) {
  const float* X        = (const float*)d_in[0];
  const float* STE      = (const float*)d_in[1];
  const int*   geo_mask = (const int*)d_in[2];
  const int*   sem_mask = (const int*)d_in[3];
  const float* PK       = (const float*)d_in[4];
  const float* Wq       = (const float*)d_in[5];
  const float* bq       = (const float*)d_in[6];
  const float* Wk       = (const float*)d_in[7];
  const float* bk       = (const float*)d_in[8];
  const float* Wv       = (const float*)d_in[9];
  const float* bv       = (const float*)d_in[10];
  const float* Wo       = (const float*)d_in[11];
  const float* bo       = (const float*)d_in[12];
  const float* Wsc      = (const float*)d_in[13];
  const float* Wwq      = (const float*)d_in[14];
  const float* Wpm      = (const float*)d_in[15];
  const float* Wpv      = (const float*)d_in[16];
  float* out = (float*)d_out;

  char* wsb = (char*)d_ws;
  short* Abf     = (short*)(wsb);                    // 24576x1024 bf16
  short* mergedb = (short*)(wsb);                    // aliases Abf (dead after QKV)
  short* Cm      = (short*)(wsb + 50331648);         // 24576x1024 bf16: q|k
  short* vT      = (short*)(wsb + 100663296);        // 512x24576 bf16
  short* Wt3     = (short*)(wsb + 125829120);        // 1536x1024 bf16
  short* Wot     = (short*)(wsb + 128974848);        // 512x512 bf16
  float* bqkv    = (float*)(wsb + 129499136);        // 1536 f32
  float* scalar  = (float*)(wsb + 129505280);        // 24576 f32
  float* mem     = (float*)(wsb + 129603584);
  float* val     = (float*)(wsb + 129619968);
  u64*   gbits   = (u64*)  (wsb + 129636352);
  u64*   sbits   = (u64*)  (wsb + 129669120);

  cast_concat_sc<<<dim3(6144), dim3(256), 0, stream>>>(X, STE, Wsc, Abf, scalar);
  prep_wqkv<<<dim3(6144), dim3(256), 0, stream>>>(Wq, Wk, Wv, Wt3);
  cast_wo<<<dim3(1024), dim3(256), 0, stream>>>(Wo, Wot);
  bias_cat<<<dim3(6), dim3(256), 0, stream>>>(bq, bk, bv, bqkv);
  pack_mask<<<dim3(1024, 2), dim3(256), 0, stream>>>(geo_mask, sem_mask, gbits, sbits);
  memval_kernel<<<dim3(Pn), dim3(256), 0, stream>>>(PK, Wpm, Wpv, mem, val);

  // merged QKV GEMM: M=24576, K=1024, N=1536 (8-phase 256^2 schedule)
  gemm256<<<dim3(576), dim3(512), 0, stream>>>(Abf, Wt3, bqkv, Cm, vT);

  // DFT branch adds into q channels [0,256)
  dft_kernel<<<dim3(Mrows / 8), dim3(256), 0, stream>>>(scalar, Wwq, mem, val, Cm);

  // flash attention
  attn2<<<dim3(3072), dim3(256), 0, stream>>>(Cm, vT, gbits, sbits, mergedb);

  // output FC: M=24576, K=512, N=512, f32 out
  gemm128o<<<dim3(768), dim3(256), 0, stream>>>(mergedb, Wot, bo, out);
}

// Round 5
// 284.770 us; speedup vs baseline: 1.0273x; 1.0273x over previous
//
#include <hip/hip_runtime.h>
#include <hip/hip_bf16.h>
#include <cstdint>

// Problem constants
#define Tn 12
#define Nn 512
#define WIN 12
#define DFT 256
#define Pn 16
#define Mrows 24576

typedef unsigned long long u64;
typedef __attribute__((ext_vector_type(8))) short short8;
typedef __attribute__((ext_vector_type(4))) float f32x4;
typedef __attribute__((address_space(1))) const void* gas1;
typedef __attribute__((address_space(3))) void* las3;

static __device__ __forceinline__ void gld16(const void* g, void* l) {
  __builtin_amdgcn_global_load_lds((gas1)g, (las3)l, 16, 0, 0);
}
static __device__ __forceinline__ short f2bf(float x) {
  __hip_bfloat16 h = __float2bfloat16(x);
  return *reinterpret_cast<short*>(&h);
}
static __device__ __forceinline__ float bf2f(short s) {
  __hip_bfloat16 h;
  *reinterpret_cast<short*>(&h) = s;
  return __bfloat162float(h);
}
static __device__ __forceinline__ f32x4 mfma16(short8 a, short8 b, f32x4 c) {
  return __builtin_amdgcn_mfma_f32_16x16x32_bf16(a, b, c, 0, 0, 0);
}

// =============== fused prep: all pre-GEMM work in ONE launch ===============
// blocks [0,6144): Wqkv transpose-cast  [6144,7168): Wo transpose-cast
// [7168,7174): bias concat              [7174,9222): mask bit-pack
// [9222,9238): mem/val                  [9238,15382): X|STE cast + scalar
__global__ __launch_bounds__(256) void prep_all(
    const float* __restrict__ X, const float* __restrict__ STE,
    const int* __restrict__ geo, const int* __restrict__ sem,
    const float* __restrict__ PK,
    const float* __restrict__ Wq, const float* __restrict__ bq,
    const float* __restrict__ Wk, const float* __restrict__ bk,
    const float* __restrict__ Wv, const float* __restrict__ bv,
    const float* __restrict__ Wo, const float* __restrict__ Wsc,
    const float* __restrict__ Wpm, const float* __restrict__ Wpv,
    short* __restrict__ Abf, short* __restrict__ Wt3, short* __restrict__ Wot,
    float* __restrict__ bqkv, float* __restrict__ scalar,
    float* __restrict__ mem, float* __restrict__ val,
    u64* __restrict__ gbits, u64* __restrict__ sbits) {
  const int bid = blockIdx.x, tid = threadIdx.x;
  if (bid < 6144) {                              // Wqkv: Wt3[n][k] = bf16(W[k][n])
    const int i = bid * 256 + tid;
    const int n = i >> 10, kk = i & 1023;
    const float* W = (n < 512) ? Wq : ((n < 1024) ? Wk : Wv);
    Wt3[(size_t)n * 1024 + kk] = f2bf(W[(size_t)kk * 512 + (n & 511)]);
  } else if (bid < 7168) {                       // Wo transpose-cast
    const int i = (bid - 6144) * 256 + tid;
    const int n = i >> 9, kk = i & 511;
    Wot[(size_t)n * 512 + kk] = f2bf(Wo[(size_t)kk * 512 + n]);
  } else if (bid < 7174) {                       // bias concat
    const int i = (bid - 7168) * 256 + tid;
    bqkv[i] = (i < 512) ? bq[i] : ((i < 1024) ? bk[i - 512] : bv[i - 1024]);
  } else if (bid < 9222) {                       // mask bit-pack
    const int pb = bid - 7174;                   // 0..2047
    const int which = pb >> 10, blk = pb & 1023;
    const int lane = tid & 63;
    const int unit = blk * 4 + (tid >> 6);       // 0..4095
    const int n = unit >> 3, seg = unit & 7;
    const int* __restrict__ src = which ? sem : geo;
    u64* __restrict__ dst = which ? sbits : gbits;
    const u64 word = __ballot(src[(size_t)n * 512 + seg * 64 + lane] != 0);
    if (lane == 0) dst[(size_t)n * 8 + seg] = word;
  } else if (bid < 9238) {                       // mem/val = PK @ Wpm/Wpv
    const int p = bid - 9222, f = tid;
    float m = 0.f, v = 0.f;
#pragma unroll
    for (int i = 0; i < WIN; ++i) {
      const float pk = PK[p * WIN + i];
      m += pk * Wpm[i * DFT + f];
      v += pk * Wpv[i * DFT + f];
    }
    mem[p * DFT + f] = m;
    val[p * DFT + f] = v;
  } else {                                       // X|STE cast + fused scalar
    const int lane = tid & 63, w = tid >> 6;
    const int m = (bid - 9238) * 4 + w;
    const int c8 = lane * 8;
    const float4 x0 = *reinterpret_cast<const float4*>(&X[(size_t)m * 512 + c8]);
    const float4 x1 = *reinterpret_cast<const float4*>(&X[(size_t)m * 512 + c8 + 4]);
    short8 xo;
    xo[0]=f2bf(x0.x); xo[1]=f2bf(x0.y); xo[2]=f2bf(x0.z); xo[3]=f2bf(x0.w);
    xo[4]=f2bf(x1.x); xo[5]=f2bf(x1.y); xo[6]=f2bf(x1.z); xo[7]=f2bf(x1.w);
    *reinterpret_cast<short8*>(&Abf[(size_t)m * 1024 + c8]) = xo;
    const float4 s0 = *reinterpret_cast<const float4*>(&STE[(size_t)m * 512 + c8]);
    const float4 s1 = *reinterpret_cast<const float4*>(&STE[(size_t)m * 512 + c8 + 4]);
    short8 so;
    so[0]=f2bf(s0.x); so[1]=f2bf(s0.y); so[2]=f2bf(s0.z); so[3]=f2bf(s0.w);
    so[4]=f2bf(s1.x); so[5]=f2bf(s1.y); so[6]=f2bf(s1.z); so[7]=f2bf(s1.w);
    *reinterpret_cast<short8*>(&Abf[(size_t)m * 1024 + 512 + c8]) = so;
    const float4 w0 = *reinterpret_cast<const float4*>(&Wsc[c8]);
    const float4 w1 = *reinterpret_cast<const float4*>(&Wsc[c8 + 4]);
    float d = x0.x*w0.x + x0.y*w0.y + x0.z*w0.z + x0.w*w0.w
            + x1.x*w1.x + x1.y*w1.y + x1.z*w1.z + x1.w*w1.w;
#pragma unroll
    for (int off = 32; off; off >>= 1) d += __shfl_xor(d, off);
    if (lane == 0) scalar[m] = d;
  }
}

// ---------------- 128x128 MFMA GEMM, global_load_lds + XOR swizzle ----------------
// MODE 1: A[M x 1024] -> Cbf [M][1024] (cols<1024, relu bf16) and vT[512][M] (cols>=1024)
// MODE 0: A[M x 512]  -> Cf  [M][512]  relu f32
template <int MODE, int NCB>
__global__ __launch_bounds__(256) void gemm128(
    const short* __restrict__ A, int lda,
    const short* __restrict__ Wt, int Ktot,
    const float* __restrict__ bias,
    short* __restrict__ Cbf, short* __restrict__ vT,
    float* __restrict__ Cf) {
  __shared__ alignas(16) short As[128 * 64];
  __shared__ alignas(16) short Bs[128 * 64];
  const int tid = threadIdx.x, lane = tid & 63, w = tid >> 6;
  const int wm = w >> 1, wn = w & 1, lg = lane >> 4, lc = lane & 15;
  const int L = blockIdx.x;
  const int x = L & 7, j = L >> 3;
  const int rp = x * 24 + j / NCB, cb = j - (j / NCB) * NCB;
  const int row0 = rp * 128, col0 = cb * 128;
  f32x4 acc[4][4];
#pragma unroll
  for (int i = 0; i < 4; ++i)
#pragma unroll
    for (int jj = 0; jj < 4; ++jj) acc[i][jj] = (f32x4){0.f, 0.f, 0.f, 0.f};

  for (int k0 = 0; k0 < Ktot; k0 += 64) {
    __syncthreads();
#pragma unroll
    for (int c = 0; c < 4; ++c) {
      const int slot0 = w * 256 + c * 64;
      const int slot = slot0 + lane;
      const int r = slot >> 3, gs = slot & 7, g = gs ^ (r & 7);
      gld16(&A[(size_t)(row0 + r) * lda + k0 + g * 8], &As[slot0 * 8]);
      gld16(&Wt[(size_t)(col0 + r) * Ktot + k0 + g * 8], &Bs[slot0 * 8]);
    }
    __syncthreads();
#pragma unroll
    for (int kh = 0; kh < 2; ++kh) {
      short8 b[4];
#pragma unroll
      for (int ns = 0; ns < 4; ++ns) {
        const int rb = wn * 64 + ns * 16 + lc;
        b[ns] = *reinterpret_cast<const short8*>(
            &Bs[(rb * 8 + ((kh * 4 + lg) ^ (rb & 7))) * 8]);
      }
#pragma unroll
      for (int ms = 0; ms < 4; ++ms) {
        const int ra = wm * 64 + ms * 16 + lc;
        const short8 a = *reinterpret_cast<const short8*>(
            &As[(ra * 8 + ((kh * 4 + lg) ^ (ra & 7))) * 8]);
#pragma unroll
        for (int ns = 0; ns < 4; ++ns) acc[ms][ns] = mfma16(a, b[ns], acc[ms][ns]);
      }
    }
  }
  // epilogue
#pragma unroll
  for (int ms = 0; ms < 4; ++ms) {
    const int rowb = row0 + wm * 64 + ms * 16 + lg * 4;
#pragma unroll
    for (int ns = 0; ns < 4; ++ns) {
      const int colg = col0 + wn * 64 + ns * 16 + lc;
      const float bv = bias[colg];
      if constexpr (MODE == 0) {
#pragma unroll
        for (int r = 0; r < 4; ++r) {
          float vv = acc[ms][ns][r] + bv;
          Cf[(size_t)(rowb + r) * 512 + colg] = vv > 0.f ? vv : 0.f;
        }
      } else {
        if (colg < 1024) {
#pragma unroll
          for (int r = 0; r < 4; ++r) {
            float vv = acc[ms][ns][r] + bv;
            Cbf[(size_t)(rowb + r) * 1024 + colg] = f2bf(vv > 0.f ? vv : 0.f);
          }
        } else {
          short4 t4;
          float vv0 = acc[ms][ns][0] + bv; t4.x = f2bf(vv0 > 0.f ? vv0 : 0.f);
          float vv1 = acc[ms][ns][1] + bv; t4.y = f2bf(vv1 > 0.f ? vv1 : 0.f);
          float vv2 = acc[ms][ns][2] + bv; t4.z = f2bf(vv2 > 0.f ? vv2 : 0.f);
          float vv3 = acc[ms][ns][3] + bv; t4.w = f2bf(vv3 > 0.f ? vv3 : 0.f);
          *reinterpret_cast<short4*>(&vT[(size_t)(colg - 1024) * Mrows + rowb]) = t4;
        }
      }
    }
  }
}

// ---- DFT branch: 16 rows/block, adds into q channels [0,256) ----
__global__ __launch_bounds__(256) void dft_kernel(
    const float* __restrict__ scalar, const float* __restrict__ Wwq,
    const float* __restrict__ mem, const float* __restrict__ val,
    short* __restrict__ q) {
  const int mrow0 = blockIdx.x * 16;
  const int bt = mrow0 >> 9;
  const int nb = mrow0 & 511;
  const int t = bt % Tn;
  const int tid = threadIdx.x;
  __shared__ float meml[16][256];
  __shared__ float vall[16][256];
  __shared__ float wl[16][12];
  __shared__ float qd[256];
  __shared__ float psum[16][17];
  __shared__ float al[16];
  for (int i = tid; i < 4096; i += 256) {
    meml[i >> 8][i & 255] = mem[i];
    vall[i >> 8][i & 255] = val[i];
  }
  if (tid < 192) {
    const int r = tid / 12, i = tid % 12;
    const int ti = t + i - (WIN - 1);
    wl[r][i] = (ti >= 0) ? scalar[(size_t)(bt + i - (WIN - 1)) * Nn + nb + r] : 0.f;
  }
  __syncthreads();
  for (int r = 0; r < 16; ++r) {
    float qf = 0.f;
#pragma unroll
    for (int i = 0; i < WIN; ++i) qf += wl[r][i] * Wwq[i * DFT + tid];
    qd[tid] = qf;
    __syncthreads();
    {
      const int p = tid >> 4, seg = tid & 15;
      float part = 0.f;
#pragma unroll
      for (int jj = 0; jj < 16; ++jj)
        part += qd[seg * 16 + jj] * meml[p][seg * 16 + jj];
      psum[p][seg] = part;
    }
    __syncthreads();
    if (tid < 16) {
      float s = 0.f;
#pragma unroll
      for (int jj = 0; jj < 16; ++jj) s += psum[tid][jj];
      s *= 0.0625f;
      float mx = s;
#pragma unroll
      for (int off = 8; off; off >>= 1) mx = fmaxf(mx, __shfl_xor(mx, off, 16));
      const float e = __expf(s - mx);
      float sum = e;
#pragma unroll
      for (int off = 8; off; off >>= 1) sum += __shfl_xor(sum, off, 16);
      al[tid] = e / sum;
    }
    __syncthreads();
    float ov = 0.f;
#pragma unroll
    for (int p2 = 0; p2 < Pn; ++p2) ov += al[p2] * vall[p2][tid];
    const size_t qi = (size_t)(mrow0 + r) * 1024 + tid;
    q[qi] = f2bf(bf2f(q[qi]) + ov);
    __syncthreads();
  }
}

// ---- MFMA flash attention v3: 128 q-rows/block, K/V fragments shared ----
// 4 waves; each wave owns 32 q-rows (2 subtiles). K/V LDS fragments are read
// once and feed BOTH q-subtiles' MFMAs (2x arithmetic density vs v2).
__global__ __launch_bounds__(256) void attn3(
    const short* __restrict__ Cm, const short* __restrict__ vT,
    const u64* __restrict__ gbits, const u64* __restrict__ sbits,
    short* __restrict__ merged) {
  const int L = blockIdx.x;            // 0..1535
  const int x = L & 7, j = L >> 3;     // j 0..191
  const int g = x * 48 + (j >> 2);     // same (head,bt) -> same XCD
  const int qt = j & 3;
  const int head = g & 7, bt = g >> 3;
  const u64* __restrict__ bits = (head < 4) ? gbits : sbits;
  const int tid = threadIdx.x, lane = tid & 63, w = tid >> 6;
  const int lg = lane >> 4, qc = lane & 15;
  const size_t rowbase = (size_t)bt * 512;
  const int n0 = qt * 128;
  const int qcol = head * 64, kcol = 512 + head * 64, vrow0 = head * 64;

  __shared__ alignas(16) short Klds[64 * 64];
  __shared__ alignas(16) short Vlds[64 * 64];
  __shared__ alignas(16) short Plds[4][2][16][72];
  __shared__ u64 mlds[128][8];

  for (int i = tid; i < 1024; i += 256)
    mlds[i >> 3][i & 7] = bits[(size_t)(n0 + (i >> 3)) * 8 + (i & 7)];

  short8 qf[2][2];
  int qrow[2];
#pragma unroll
  for (int qs = 0; qs < 2; ++qs) {
    qrow[qs] = n0 + w * 32 + qs * 16 + qc;
    qf[qs][0] = *reinterpret_cast<const short8*>(
        &Cm[(rowbase + qrow[qs]) * 1024 + qcol + lg * 8]);
    qf[qs][1] = *reinterpret_cast<const short8*>(
        &Cm[(rowbase + qrow[qs]) * 1024 + qcol + 32 + lg * 8]);
  }

  float m_run[2] = {-1e30f, -1e30f}, l_run[2] = {0.f, 0.f};
  f32x4 o[2][4];
#pragma unroll
  for (int qs = 0; qs < 2; ++qs)
#pragma unroll
    for (int i = 0; i < 4; ++i) o[qs][i] = (f32x4){0.f, 0.f, 0.f, 0.f};

  for (int ch = 0; ch < 8; ++ch) {
    __syncthreads();
#pragma unroll
    for (int c = 0; c < 2; ++c) {
      const int slot0 = (w * 2 + c) * 64;
      const int slot = slot0 + lane;
      const int r = slot >> 3, gs = slot & 7, gg = gs ^ (r & 7);
      gld16(&Cm[(rowbase + ch * 64 + r) * 1024 + kcol + gg * 8], &Klds[slot0 * 8]);
      gld16(&vT[(size_t)(vrow0 + r) * Mrows + rowbase + ch * 64 + gg * 8],
            &Vlds[slot0 * 8]);
    }
    __syncthreads();

    // S^T = K . Q^T for both q-subtiles, K fragments shared
    u64 mw[2];
    mw[0] = mlds[w * 32 + qc][ch];
    mw[1] = mlds[w * 32 + 16 + qc][ch];
    float p[2][4][4];
    float cm0 = -1e30f, cm1 = -1e30f;
#pragma unroll
    for (int s = 0; s < 4; ++s) {
      const int rk = s * 16 + qc;
      const short8 a0 = *reinterpret_cast<const short8*>(
          &Klds[(rk * 8 + (lg ^ (rk & 7))) * 8]);
      const short8 a1 = *reinterpret_cast<const short8*>(
          &Klds[(rk * 8 + ((4 + lg) ^ (rk & 7))) * 8]);
      f32x4 sa0 = (f32x4){0.f, 0.f, 0.f, 0.f};
      f32x4 sa1 = (f32x4){0.f, 0.f, 0.f, 0.f};
      __builtin_amdgcn_s_setprio(1);
      sa0 = mfma16(a0, qf[0][0], sa0);
      sa0 = mfma16(a1, qf[0][1], sa0);
      sa1 = mfma16(a0, qf[1][0], sa1);
      sa1 = mfma16(a1, qf[1][1], sa1);
      __builtin_amdgcn_s_setprio(0);
#pragma unroll
      for (int r = 0; r < 4; ++r) {
        const int kb = s * 16 + lg * 4 + r;
        const float sv0 = ((mw[0] >> kb) & 1ull) ? sa0[r] * 0.125f : -1e30f;
        const float sv1 = ((mw[1] >> kb) & 1ull) ? sa1[r] * 0.125f : -1e30f;
        p[0][s][r] = sv0; cm0 = fmaxf(cm0, sv0);
        p[1][s][r] = sv1; cm1 = fmaxf(cm1, sv1);
      }
    }
    float cms[2] = {cm0, cm1};
#pragma unroll
    for (int qs = 0; qs < 2; ++qs) {
      float cm = cms[qs];
      cm = fmaxf(cm, __shfl_xor(cm, 16));
      cm = fmaxf(cm, __shfl_xor(cm, 32));
      if (__any(cm > m_run[qs])) {
        const float m_new = fmaxf(m_run[qs], cm);
        const float alpha = __expf(m_run[qs] - m_new);
        l_run[qs] *= alpha;
#pragma unroll
        for (int i = 0; i < 4; ++i) o[qs][i] *= alpha;
        m_run[qs] = m_new;
      }
      float csum = 0.f;
#pragma unroll
      for (int s = 0; s < 4; ++s) {
        short4 p4;
        float pv0 = (p[qs][s][0] > -1e29f) ? __expf(p[qs][s][0] - m_run[qs]) : 0.f;
        float pv1 = (p[qs][s][1] > -1e29f) ? __expf(p[qs][s][1] - m_run[qs]) : 0.f;
        float pv2 = (p[qs][s][2] > -1e29f) ? __expf(p[qs][s][2] - m_run[qs]) : 0.f;
        float pv3 = (p[qs][s][3] > -1e29f) ? __expf(p[qs][s][3] - m_run[qs]) : 0.f;
        csum += pv0 + pv1 + pv2 + pv3;
        p4.x = f2bf(pv0); p4.y = f2bf(pv1); p4.z = f2bf(pv2); p4.w = f2bf(pv3);
        *reinterpret_cast<short4*>(&Plds[w][qs][qc][s * 16 + lg * 4]) = p4;
      }
      csum += __shfl_xor(csum, 16);
      csum += __shfl_xor(csum, 32);
      l_run[qs] += csum;
    }

    // O^T += V^T . P^T, V fragments shared across q-subtiles
#pragma unroll
    for (int kh = 0; kh < 2; ++kh) {
      const short8 pb0 = *reinterpret_cast<const short8*>(
          &Plds[w][0][qc][kh * 32 + lg * 8]);
      const short8 pb1 = *reinterpret_cast<const short8*>(
          &Plds[w][1][qc][kh * 32 + lg * 8]);
      __builtin_amdgcn_s_setprio(1);
#pragma unroll
      for (int ds = 0; ds < 4; ++ds) {
        const int rd = ds * 16 + qc;
        const short8 va = *reinterpret_cast<const short8*>(
            &Vlds[(rd * 8 + ((kh * 4 + lg) ^ (rd & 7))) * 8]);
        o[0][ds] = mfma16(va, pb0, o[0][ds]);
        o[1][ds] = mfma16(va, pb1, o[1][ds]);
      }
      __builtin_amdgcn_s_setprio(0);
    }
  }
#pragma unroll
  for (int qs = 0; qs < 2; ++qs) {
    const float inv = l_run[qs] > 0.f ? 1.f / l_run[qs] : 0.f;
#pragma unroll
    for (int ds = 0; ds < 4; ++ds) {
      short4 t4;
      t4.x = f2bf(o[qs][ds][0] * inv);
      t4.y = f2bf(o[qs][ds][1] * inv);
      t4.z = f2bf(o[qs][ds][2] * inv);
      t4.w = f2bf(o[qs][ds][3] * inv);
      *reinterpret_cast<short4*>(
          &merged[(rowbase + qrow[qs]) * 512 + head * 64 + ds * 16 + lg * 4]) = t4;
    }
  }
}

// ---------------- launch ----------------
extern "C" void kernel_launch(void* const* d_in, const int* in_sizes, int n_in,
                              void* d_out, int out_size, void* d_ws, size_t ws_size,
                              hipStream_t stream) {
  const float* X        = (const float*)d_in[0];
  const float* STE      = (const float*)d_in[1];
  const int*   geo_mask = (const int*)d_in[2];
  const int*   sem_mask = (const int*)d_in[3];
  const float* PK       = (const float*)d_in[4];
  const float* Wq       = (const float*)d_in[5];
  const float* bq       = (const float*)d_in[6];
  const float* Wk       = (const float*)d_in[7];
  const float* bk       = (const float*)d_in[8];
  const float* Wv       = (const float*)d_in[9];
  const float* bv       = (const float*)d_in[10];
  const float* Wo       = (const float*)d_in[11];
  const float* bo       = (const float*)d_in[12];
  const float* Wsc      = (const float*)d_in[13];
  const float* Wwq      = (const float*)d_in[14];
  const float* Wpm      = (const float*)d_in[15];
  const float* Wpv      = (const float*)d_in[16];
  float* out = (float*)d_out;

  char* wsb = (char*)d_ws;
  short* Abf     = (short*)(wsb);                    // 24576x1024 bf16
  short* mergedb = (short*)(wsb);                    // aliases Abf (dead after QKV)
  short* Cm      = (short*)(wsb + 50331648);         // 24576x1024 bf16: q|k
  short* vT      = (short*)(wsb + 100663296);        // 512x24576 bf16
  short* Wt3     = (short*)(wsb + 125829120);        // 1536x1024 bf16
  short* Wot     = (short*)(wsb + 128974848);        // 512x512 bf16
  float* bqkv    = (float*)(wsb + 129499136);        // 1536 f32
  float* scalar  = (float*)(wsb + 129505280);        // 24576 f32
  float* mem     = (float*)(wsb + 129603584);
  float* val     = (float*)(wsb + 129619968);
  u64*   gbits   = (u64*)  (wsb + 129636352);
  u64*   sbits   = (u64*)  (wsb + 129669120);

  // all prep in one launch
  prep_all<<<dim3(15382), dim3(256), 0, stream>>>(
      X, STE, geo_mask, sem_mask, PK, Wq, bq, Wk, bk, Wv, bv, Wo, Wsc, Wpm, Wpv,
      Abf, Wt3, Wot, bqkv, scalar, mem, val, gbits, sbits);

  // merged QKV GEMM: M=24576, K=1024, N=1536 (writes Cm q|k + vT transposed)
  gemm128<1, 12><<<dim3(2304), dim3(256), 0, stream>>>(
      Abf, 1024, Wt3, 1024, bqkv, Cm, vT, nullptr);

  // DFT branch adds into q channels [0,256)
  dft_kernel<<<dim3(Mrows / 16), dim3(256), 0, stream>>>(scalar, Wwq, mem, val, Cm);

  // flash attention (128 q-rows per block)
  attn3<<<dim3(1536), dim3(256), 0, stream>>>(Cm, vT, gbits, sbits, mergedb);

  // output FC: M=24576, K=512, N=512, f32 out
  gemm128<0, 4><<<dim3(768), dim3(256), 0, stream>>>(
      mergedb, 512, Wot, 512, bo, nullptr, nullptr, out);
}

// Round 6
// 254.250 us; speedup vs baseline: 1.1506x; 1.1200x over previous
//
#include <hip/hip_runtime.h>
#include <hip/hip_bf16.h>
#include <cstdint>

// Problem constants
#define Tn 12
#define Nn 512
#define WIN 12
#define DFT 256
#define Pn 16
#define Mrows 24576

typedef unsigned long long u64;
typedef __attribute__((ext_vector_type(8))) short short8;
typedef __attribute__((ext_vector_type(4))) float f32x4;
typedef __attribute__((address_space(1))) const void* gas1;
typedef __attribute__((address_space(3))) void* las3;

static __device__ __forceinline__ void gld16(const void* g, void* l) {
  __builtin_amdgcn_global_load_lds((gas1)g, (las3)l, 16, 0, 0);
}
static __device__ __forceinline__ short f2bf(float x) {
  __hip_bfloat16 h = __float2bfloat16(x);
  return *reinterpret_cast<short*>(&h);
}
static __device__ __forceinline__ float bf2f(short s) {
  __hip_bfloat16 h;
  *reinterpret_cast<short*>(&h) = s;
  return __bfloat162float(h);
}
static __device__ __forceinline__ f32x4 mfma16(short8 a, short8 b, f32x4 c) {
  return __builtin_amdgcn_mfma_f32_16x16x32_bf16(a, b, c, 0, 0, 0);
}

// =============== fused prep: all pre-GEMM work in ONE launch ===============
// [0,6144): X|STE cast + fused scalar   [6144,8192): mask bit-pack
// [8192,8640): LDS-tiled weight transpose-cast  [8640,8646): bias concat
// [8646,8662): mem/val
__global__ __launch_bounds__(256) void prep_all(
    const float* __restrict__ X, const float* __restrict__ STE,
    const int* __restrict__ geo, const int* __restrict__ sem,
    const float* __restrict__ PK,
    const float* __restrict__ Wq, const float* __restrict__ bq,
    const float* __restrict__ Wk, const float* __restrict__ bk,
    const float* __restrict__ Wv, const float* __restrict__ bv,
    const float* __restrict__ Wo, const float* __restrict__ Wsc,
    const float* __restrict__ Wpm, const float* __restrict__ Wpv,
    short* __restrict__ Abf, short* __restrict__ Wt3, short* __restrict__ Wot,
    float* __restrict__ bqkv, float* __restrict__ scalar,
    float* __restrict__ mem, float* __restrict__ val,
    u64* __restrict__ gbits, u64* __restrict__ sbits) {
  __shared__ float tl[64][65];   // only used by transpose branch
  const int bid = blockIdx.x, tid = threadIdx.x;
  if (bid < 6144) {                              // X|STE cast + fused scalar
    const int lane = tid & 63, w = tid >> 6;
    const int m = bid * 4 + w;
    const int c8 = lane * 8;
    const float4 x0 = *reinterpret_cast<const float4*>(&X[(size_t)m * 512 + c8]);
    const float4 x1 = *reinterpret_cast<const float4*>(&X[(size_t)m * 512 + c8 + 4]);
    short8 xo;
    xo[0]=f2bf(x0.x); xo[1]=f2bf(x0.y); xo[2]=f2bf(x0.z); xo[3]=f2bf(x0.w);
    xo[4]=f2bf(x1.x); xo[5]=f2bf(x1.y); xo[6]=f2bf(x1.z); xo[7]=f2bf(x1.w);
    *reinterpret_cast<short8*>(&Abf[(size_t)m * 1024 + c8]) = xo;
    const float4 s0 = *reinterpret_cast<const float4*>(&STE[(size_t)m * 512 + c8]);
    const float4 s1 = *reinterpret_cast<const float4*>(&STE[(size_t)m * 512 + c8 + 4]);
    short8 so;
    so[0]=f2bf(s0.x); so[1]=f2bf(s0.y); so[2]=f2bf(s0.z); so[3]=f2bf(s0.w);
    so[4]=f2bf(s1.x); so[5]=f2bf(s1.y); so[6]=f2bf(s1.z); so[7]=f2bf(s1.w);
    *reinterpret_cast<short8*>(&Abf[(size_t)m * 1024 + 512 + c8]) = so;
    const float4 w0 = *reinterpret_cast<const float4*>(&Wsc[c8]);
    const float4 w1 = *reinterpret_cast<const float4*>(&Wsc[c8 + 4]);
    float d = x0.x*w0.x + x0.y*w0.y + x0.z*w0.z + x0.w*w0.w
            + x1.x*w1.x + x1.y*w1.y + x1.z*w1.z + x1.w*w1.w;
#pragma unroll
    for (int off = 32; off; off >>= 1) d += __shfl_xor(d, off);
    if (lane == 0) scalar[m] = d;
  } else if (bid < 8192) {                       // mask bit-pack
    const int pb = bid - 6144;                   // 0..2047
    const int which = pb >> 10, blk = pb & 1023;
    const int lane = tid & 63;
    const int unit = blk * 4 + (tid >> 6);       // 0..4095
    const int n = unit >> 3, seg = unit & 7;
    const int* __restrict__ src = which ? sem : geo;
    u64* __restrict__ dst = which ? sbits : gbits;
    const u64 word = __ballot(src[(size_t)n * 512 + seg * 64 + lane] != 0);
    if (lane == 0) dst[(size_t)n * 8 + seg] = word;
  } else if (bid < 8640) {                       // tiled weight transpose-cast
    const int ti0 = bid - 8192;                  // 0..447
    const float* W;
    short* out;
    int kt, nt, ldk;
    if (ti0 < 384) {
      const int mi = ti0 / 128, ti = ti0 % 128;
      W = (mi == 0) ? Wq : ((mi == 1) ? Wk : Wv);
      out = Wt3 + (size_t)mi * 512 * 1024;
      kt = ti >> 3; nt = ti & 7; ldk = 1024;     // W is 1024x512
    } else {
      const int ti = ti0 - 384;
      W = Wo; out = Wot;
      kt = ti >> 3; nt = ti & 7; ldk = 512;      // W is 512x512
    }
    const int k0 = kt * 64, n0 = nt * 64;
    {
      const int r = tid >> 2, c0 = (tid & 3) * 16;
#pragma unroll
      for (int u = 0; u < 4; ++u) {
        const float4 v = *reinterpret_cast<const float4*>(
            &W[(size_t)(k0 + r) * 512 + n0 + c0 + u * 4]);
        tl[r][c0+u*4+0]=v.x; tl[r][c0+u*4+1]=v.y; tl[r][c0+u*4+2]=v.z; tl[r][c0+u*4+3]=v.w;
      }
    }
    __syncthreads();
    {
      const int nn = tid >> 2, c0 = (tid & 3) * 16;
      short8 o0, o1;
#pragma unroll
      for (int u = 0; u < 8; ++u) o0[u] = f2bf(tl[c0 + u][nn]);
#pragma unroll
      for (int u = 0; u < 8; ++u) o1[u] = f2bf(tl[c0 + 8 + u][nn]);
      *reinterpret_cast<short8*>(&out[(size_t)(n0 + nn) * ldk + k0 + c0]) = o0;
      *reinterpret_cast<short8*>(&out[(size_t)(n0 + nn) * ldk + k0 + c0 + 8]) = o1;
    }
  } else if (bid < 8646) {                       // bias concat
    const int i = (bid - 8640) * 256 + tid;
    bqkv[i] = (i < 512) ? bq[i] : ((i < 1024) ? bk[i - 512] : bv[i - 1024]);
  } else {                                       // mem/val = PK @ Wpm/Wpv
    const int p = bid - 8646, f = tid;
    float m = 0.f, v = 0.f;
#pragma unroll
    for (int i = 0; i < WIN; ++i) {
      const float pk = PK[p * WIN + i];
      m += pk * Wpm[i * DFT + f];
      v += pk * Wpv[i * DFT + f];
    }
    mem[p * DFT + f] = m;
    val[p * DFT + f] = v;
  }
}

// ---------------- 128x128 MFMA GEMM, global_load_lds + XOR swizzle ----------------
// MODE 1: A[M x 1024] -> Cbf [M][1024] (cols<1024, relu bf16) and vT[512][M] (cols>=1024)
// MODE 0: A[M x 512]  -> Cf  [M][512]  relu f32
template <int MODE, int NCB>
__global__ __launch_bounds__(256) void gemm128(
    const short* __restrict__ A, int lda,
    const short* __restrict__ Wt, int Ktot,
    const float* __restrict__ bias,
    short* __restrict__ Cbf, short* __restrict__ vT,
    float* __restrict__ Cf) {
  __shared__ alignas(16) short As[128 * 64];
  __shared__ alignas(16) short Bs[128 * 64];
  const int tid = threadIdx.x, lane = tid & 63, w = tid >> 6;
  const int wm = w >> 1, wn = w & 1, lg = lane >> 4, lc = lane & 15;
  const int L = blockIdx.x;
  const int x = L & 7, j = L >> 3;
  const int rp = x * 24 + j / NCB, cb = j - (j / NCB) * NCB;
  const int row0 = rp * 128, col0 = cb * 128;
  f32x4 acc[4][4];
#pragma unroll
  for (int i = 0; i < 4; ++i)
#pragma unroll
    for (int jj = 0; jj < 4; ++jj) acc[i][jj] = (f32x4){0.f, 0.f, 0.f, 0.f};

  for (int k0 = 0; k0 < Ktot; k0 += 64) {
    __syncthreads();
#pragma unroll
    for (int c = 0; c < 4; ++c) {
      const int slot0 = w * 256 + c * 64;
      const int slot = slot0 + lane;
      const int r = slot >> 3, gs = slot & 7, g = gs ^ (r & 7);
      gld16(&A[(size_t)(row0 + r) * lda + k0 + g * 8], &As[slot0 * 8]);
      gld16(&Wt[(size_t)(col0 + r) * Ktot + k0 + g * 8], &Bs[slot0 * 8]);
    }
    __syncthreads();
#pragma unroll
    for (int kh = 0; kh < 2; ++kh) {
      short8 b[4];
#pragma unroll
      for (int ns = 0; ns < 4; ++ns) {
        const int rb = wn * 64 + ns * 16 + lc;
        b[ns] = *reinterpret_cast<const short8*>(
            &Bs[(rb * 8 + ((kh * 4 + lg) ^ (rb & 7))) * 8]);
      }
#pragma unroll
      for (int ms = 0; ms < 4; ++ms) {
        const int ra = wm * 64 + ms * 16 + lc;
        const short8 a = *reinterpret_cast<const short8*>(
            &As[(ra * 8 + ((kh * 4 + lg) ^ (ra & 7))) * 8]);
#pragma unroll
        for (int ns = 0; ns < 4; ++ns) acc[ms][ns] = mfma16(a, b[ns], acc[ms][ns]);
      }
    }
  }
  // epilogue
#pragma unroll
  for (int ms = 0; ms < 4; ++ms) {
    const int rowb = row0 + wm * 64 + ms * 16 + lg * 4;
#pragma unroll
    for (int ns = 0; ns < 4; ++ns) {
      const int colg = col0 + wn * 64 + ns * 16 + lc;
      const float bv = bias[colg];
      if constexpr (MODE == 0) {
#pragma unroll
        for (int r = 0; r < 4; ++r) {
          float vv = acc[ms][ns][r] + bv;
          Cf[(size_t)(rowb + r) * 512 + colg] = vv > 0.f ? vv : 0.f;
        }
      } else {
        if (colg < 1024) {
#pragma unroll
          for (int r = 0; r < 4; ++r) {
            float vv = acc[ms][ns][r] + bv;
            Cbf[(size_t)(rowb + r) * 1024 + colg] = f2bf(vv > 0.f ? vv : 0.f);
          }
        } else {
          short4 t4;
          float vv0 = acc[ms][ns][0] + bv; t4.x = f2bf(vv0 > 0.f ? vv0 : 0.f);
          float vv1 = acc[ms][ns][1] + bv; t4.y = f2bf(vv1 > 0.f ? vv1 : 0.f);
          float vv2 = acc[ms][ns][2] + bv; t4.z = f2bf(vv2 > 0.f ? vv2 : 0.f);
          float vv3 = acc[ms][ns][3] + bv; t4.w = f2bf(vv3 > 0.f ? vv3 : 0.f);
          *reinterpret_cast<short4*>(&vT[(size_t)(colg - 1024) * Mrows + rowb]) = t4;
        }
      }
    }
  }
}

// ---- DFT branch v2: wave-parallel, barrier-free after staging ----
// One row per wave per iteration; 4 waves x 8 iters = 32 rows/block.
__global__ __launch_bounds__(256) void dft2(
    const float* __restrict__ scalar, const float* __restrict__ Wwq,
    const float* __restrict__ mem, const float* __restrict__ val,
    short* __restrict__ q) {
  __shared__ float wwql[12][256];
  __shared__ float meml[16][260];
  __shared__ float vall[16][260];
  __shared__ float qdl[4][256];
  const int tid = threadIdx.x, lane = tid & 63, w = tid >> 6;
  for (int i = tid; i < 3072; i += 256) wwql[0][i] = Wwq[i];   // [12][256] flat
  for (int i = tid; i < 4096; i += 256) {
    meml[i >> 8][i & 255] = mem[i];
    vall[i >> 8][i & 255] = val[i];
  }
  __syncthreads();
  const int mrow0 = blockIdx.x * 32;
  const int bt = mrow0 >> 9;      // 32 rows stay within one bt (512-aligned)
  const int t = bt % Tn;
  const int p = lane & 15, sg = lane >> 4;
#pragma unroll 1
  for (int it = 0; it < 8; ++it) {
    const int mrow = mrow0 + w * 8 + it;
    const int n = mrow & 511;
    // windows (broadcast loads, same addr across lanes)
    float wl[12];
#pragma unroll
    for (int i = 0; i < 12; ++i) {
      const int ti = t + i - (WIN - 1);
      wl[i] = (ti >= 0) ? scalar[(size_t)(bt + i - (WIN - 1)) * Nn + n] : 0.f;
    }
    // qd: 4 features per lane
    float4 qd = {0.f, 0.f, 0.f, 0.f};
#pragma unroll
    for (int i = 0; i < 12; ++i) {
      const float4 wv = *reinterpret_cast<const float4*>(&wwql[i][lane * 4]);
      qd.x += wl[i] * wv.x; qd.y += wl[i] * wv.y;
      qd.z += wl[i] * wv.z; qd.w += wl[i] * wv.w;
    }
    *reinterpret_cast<float4*>(&qdl[w][lane * 4]) = qd;
    asm volatile("s_waitcnt lgkmcnt(0)" ::: "memory");
    // ps partial: lane (p, sg) covers f in [sg*64, sg*64+64)
    float ps = 0.f;
#pragma unroll
    for (int ff = 0; ff < 16; ++ff) {
      const float4 qv = *reinterpret_cast<const float4*>(&qdl[w][sg * 64 + ff * 4]);
      const float4 mv = *reinterpret_cast<const float4*>(&meml[p][sg * 64 + ff * 4]);
      ps += qv.x * mv.x + qv.y * mv.y + qv.z * mv.z + qv.w * mv.w;
    }
    ps += __shfl_xor(ps, 16);
    ps += __shfl_xor(ps, 32);
    // softmax over 16 patterns (value for p in every lane, dup 4x)
    const float s = ps * 0.0625f;
    float mx = s;
#pragma unroll
    for (int off = 1; off < 16; off <<= 1) mx = fmaxf(mx, __shfl_xor(mx, off));
    const float e = __expf(s - mx);
    float den = e;
#pragma unroll
    for (int off = 1; off < 16; off <<= 1) den += __shfl_xor(den, off);
    const float a = e / den;
    // out: 4 features per lane; a[pp] broadcast via readlane
    float4 o = {0.f, 0.f, 0.f, 0.f};
#pragma unroll
    for (int pp = 0; pp < 16; ++pp) {
      const float ap = __shfl(a, pp);
      const float4 vv = *reinterpret_cast<const float4*>(&vall[pp][lane * 4]);
      o.x += ap * vv.x; o.y += ap * vv.y; o.z += ap * vv.z; o.w += ap * vv.w;
    }
    const size_t qi = (size_t)mrow * 1024 + lane * 4;
    short4 qo = *reinterpret_cast<const short4*>(&q[qi]);
    short4 qn;
    qn.x = f2bf(bf2f(qo.x) + o.x);
    qn.y = f2bf(bf2f(qo.y) + o.y);
    qn.z = f2bf(bf2f(qo.z) + o.z);
    qn.w = f2bf(bf2f(qo.w) + o.w);
    *reinterpret_cast<short4*>(&q[qi]) = qn;
  }
}

// ---- MFMA flash attention v4: 128 q-rows/block + K/V LDS double-buffer ----
#define ASTAGE(B, CH) { \
  _Pragma("unroll") for (int c = 0; c < 2; ++c) { \
    const int slot0 = (w * 2 + c) * 64; \
    const int slot = slot0 + lane; \
    const int r = slot >> 3, gs = slot & 7, gg = gs ^ (r & 7); \
    gld16(&Cm[(rowbase + (CH) * 64 + r) * 1024 + kcol + gg * 8], &Klds[B][slot0 * 8]); \
    gld16(&vT[(size_t)(vrow0 + r) * Mrows + rowbase + (CH) * 64 + gg * 8], \
          &Vlds[B][slot0 * 8]); } }

__global__ __launch_bounds__(256) void attn4(
    const short* __restrict__ Cm, const short* __restrict__ vT,
    const u64* __restrict__ gbits, const u64* __restrict__ sbits,
    short* __restrict__ merged) {
  const int L = blockIdx.x;            // 0..1535
  const int x = L & 7, j = L >> 3;     // j 0..191
  const int g = x * 48 + (j >> 2);     // same (head,bt) -> same XCD
  const int qt = j & 3;
  const int head = g & 7, bt = g >> 3;
  const u64* __restrict__ bits = (head < 4) ? gbits : sbits;
  const int tid = threadIdx.x, lane = tid & 63, w = tid >> 6;
  const int lg = lane >> 4, qc = lane & 15;
  const size_t rowbase = (size_t)bt * 512;
  const int n0 = qt * 128;
  const int qcol = head * 64, kcol = 512 + head * 64, vrow0 = head * 64;

  __shared__ alignas(16) short Klds[2][4096];
  __shared__ alignas(16) short Vlds[2][4096];
  __shared__ alignas(16) short Plds[4][2][16][72];

  short8 qf[2][2];
  int qrow[2];
#pragma unroll
  for (int qs = 0; qs < 2; ++qs) {
    qrow[qs] = n0 + w * 32 + qs * 16 + qc;
    qf[qs][0] = *reinterpret_cast<const short8*>(
        &Cm[(rowbase + qrow[qs]) * 1024 + qcol + lg * 8]);
    qf[qs][1] = *reinterpret_cast<const short8*>(
        &Cm[(rowbase + qrow[qs]) * 1024 + qcol + 32 + lg * 8]);
  }

  float m_run[2] = {-1e30f, -1e30f}, l_run[2] = {0.f, 0.f};
  f32x4 o[2][4];
#pragma unroll
  for (int qs = 0; qs < 2; ++qs)
#pragma unroll
    for (int i = 0; i < 4; ++i) o[qs][i] = (f32x4){0.f, 0.f, 0.f, 0.f};

  ASTAGE(0, 0);
  u64 mw0 = bits[(size_t)(n0 + w * 32 + qc) * 8];
  u64 mw1 = bits[(size_t)(n0 + w * 32 + 16 + qc) * 8];
  asm volatile("s_waitcnt vmcnt(0)" ::: "memory");
  __syncthreads();

  int cur = 0;
#pragma unroll 1
  for (int ch = 0; ch < 8; ++ch) {
    if (ch < 7) ASTAGE(cur ^ 1, ch + 1);            // prefetch next chunk
    u64 nmw0 = 0, nmw1 = 0;
    if (ch < 7) {                                    // prefetch next masks
      nmw0 = bits[(size_t)(n0 + w * 32 + qc) * 8 + ch + 1];
      nmw1 = bits[(size_t)(n0 + w * 32 + 16 + qc) * 8 + ch + 1];
    }
    // S^T = K . Q^T for both q-subtiles, K fragments shared
    float p[2][4][4];
    float cm0 = -1e30f, cm1 = -1e30f;
#pragma unroll
    for (int s = 0; s < 4; ++s) {
      const int rk = s * 16 + qc;
      const short8 a0 = *reinterpret_cast<const short8*>(
          &Klds[cur][(rk * 8 + (lg ^ (rk & 7))) * 8]);
      const short8 a1 = *reinterpret_cast<const short8*>(
          &Klds[cur][(rk * 8 + ((4 + lg) ^ (rk & 7))) * 8]);
      f32x4 sa0 = (f32x4){0.f, 0.f, 0.f, 0.f};
      f32x4 sa1 = (f32x4){0.f, 0.f, 0.f, 0.f};
      __builtin_amdgcn_s_setprio(1);
      sa0 = mfma16(a0, qf[0][0], sa0);
      sa0 = mfma16(a1, qf[0][1], sa0);
      sa1 = mfma16(a0, qf[1][0], sa1);
      sa1 = mfma16(a1, qf[1][1], sa1);
      __builtin_amdgcn_s_setprio(0);
#pragma unroll
      for (int r = 0; r < 4; ++r) {
        const int kb = s * 16 + lg * 4 + r;
        const float sv0 = ((mw0 >> kb) & 1ull) ? sa0[r] * 0.125f : -1e30f;
        const float sv1 = ((mw1 >> kb) & 1ull) ? sa1[r] * 0.125f : -1e30f;
        p[0][s][r] = sv0; cm0 = fmaxf(cm0, sv0);
        p[1][s][r] = sv1; cm1 = fmaxf(cm1, sv1);
      }
    }
    float cms[2] = {cm0, cm1};
#pragma unroll
    for (int qs = 0; qs < 2; ++qs) {
      float cm = cms[qs];
      cm = fmaxf(cm, __shfl_xor(cm, 16));
      cm = fmaxf(cm, __shfl_xor(cm, 32));
      if (__any(cm > m_run[qs])) {
        const float m_new = fmaxf(m_run[qs], cm);
        const float alpha = __expf(m_run[qs] - m_new);
        l_run[qs] *= alpha;
#pragma unroll
        for (int i = 0; i < 4; ++i) o[qs][i] *= alpha;
        m_run[qs] = m_new;
      }
      float csum = 0.f;
#pragma unroll
      for (int s = 0; s < 4; ++s) {
        short4 p4;
        float pv0 = (p[qs][s][0] > -1e29f) ? __expf(p[qs][s][0] - m_run[qs]) : 0.f;
        float pv1 = (p[qs][s][1] > -1e29f) ? __expf(p[qs][s][1] - m_run[qs]) : 0.f;
        float pv2 = (p[qs][s][2] > -1e29f) ? __expf(p[qs][s][2] - m_run[qs]) : 0.f;
        float pv3 = (p[qs][s][3] > -1e29f) ? __expf(p[qs][s][3] - m_run[qs]) : 0.f;
        csum += pv0 + pv1 + pv2 + pv3;
        p4.x = f2bf(pv0); p4.y = f2bf(pv1); p4.z = f2bf(pv2); p4.w = f2bf(pv3);
        *reinterpret_cast<short4*>(&Plds[w][qs][qc][s * 16 + lg * 4]) = p4;
      }
      csum += __shfl_xor(csum, 16);
      csum += __shfl_xor(csum, 32);
      l_run[qs] += csum;
    }

    // O^T += V^T . P^T, V fragments shared across q-subtiles
#pragma unroll
    for (int kh = 0; kh < 2; ++kh) {
      const short8 pb0 = *reinterpret_cast<const short8*>(
          &Plds[w][0][qc][kh * 32 + lg * 8]);
      const short8 pb1 = *reinterpret_cast<const short8*>(
          &Plds[w][1][qc][kh * 32 + lg * 8]);
      __builtin_amdgcn_s_setprio(1);
#pragma unroll
      for (int ds = 0; ds < 4; ++ds) {
        const int rd = ds * 16 + qc;
        const short8 va = *reinterpret_cast<const short8*>(
            &Vlds[cur][(rd * 8 + ((kh * 4 + lg) ^ (rd & 7))) * 8]);
        o[0][ds] = mfma16(va, pb0, o[0][ds]);
        o[1][ds] = mfma16(va, pb1, o[1][ds]);
      }
      __builtin_amdgcn_s_setprio(0);
    }
    asm volatile("s_waitcnt vmcnt(0)" ::: "memory");   // next chunk landed
    __syncthreads();                                    // all waves done with cur
    cur ^= 1;
    mw0 = nmw0; mw1 = nmw1;
  }
#pragma unroll
  for (int qs = 0; qs < 2; ++qs) {
    const float inv = l_run[qs] > 0.f ? 1.f / l_run[qs] : 0.f;
#pragma unroll
    for (int ds = 0; ds < 4; ++ds) {
      short4 t4;
      t4.x = f2bf(o[qs][ds][0] * inv);
      t4.y = f2bf(o[qs][ds][1] * inv);
      t4.z = f2bf(o[qs][ds][2] * inv);
      t4.w = f2bf(o[qs][ds][3] * inv);
      *reinterpret_cast<short4*>(
          &merged[(rowbase + qrow[qs]) * 512 + head * 64 + ds * 16 + lg * 4]) = t4;
    }
  }
}

// ---------------- launch ----------------
extern "C" void kernel_launch(void* const* d_in, const int* in_sizes, int n_in,
                              void* d_out, int out_size, void* d_ws, size_t ws_size,
                              hipStream_t stream) {
  const float* X        = (const float*)d_in[0];
  const float* STE      = (const float*)d_in[1];
  const int*   geo_mask = (const int*)d_in[2];
  const int*   sem_mask = (const int*)d_in[3];
  const float* PK       = (const float*)d_in[4];
  const float* Wq       = (const float*)d_in[5];
  const float* bq       = (const float*)d_in[6];
  const float* Wk       = (const float*)d_in[7];
  const float* bk       = (const float*)d_in[8];
  const float* Wv       = (const float*)d_in[9];
  const float* bv       = (const float*)d_in[10];
  const float* Wo       = (const float*)d_in[11];
  const float* bo       = (const float*)d_in[12];
  const float* Wsc      = (const float*)d_in[13];
  const float* Wwq      = (const float*)d_in[14];
  const float* Wpm      = (const float*)d_in[15];
  const float* Wpv      = (const float*)d_in[16];
  float* out = (float*)d_out;

  char* wsb = (char*)d_ws;
  short* Abf     = (short*)(wsb);                    // 24576x1024 bf16
  short* mergedb = (short*)(wsb);                    // aliases Abf (dead after QKV)
  short* Cm      = (short*)(wsb + 50331648);         // 24576x1024 bf16: q|k
  short* vT      = (short*)(wsb + 100663296);        // 512x24576 bf16
  short* Wt3     = (short*)(wsb + 125829120);        // 1536x1024 bf16
  short* Wot     = (short*)(wsb + 128974848);        // 512x512 bf16
  float* bqkv    = (float*)(wsb + 129499136);        // 1536 f32
  float* scalar  = (float*)(wsb + 129505280);        // 24576 f32
  float* mem     = (float*)(wsb + 129603584);
  float* val     = (float*)(wsb + 129619968);
  u64*   gbits   = (u64*)  (wsb + 129636352);
  u64*   sbits   = (u64*)  (wsb + 129669120);

  // all prep in one launch (cast+scalar | masks | tiled W transpose | bias | mem/val)
  prep_all<<<dim3(8662), dim3(256), 0, stream>>>(
      X, STE, geo_mask, sem_mask, PK, Wq, bq, Wk, bk, Wv, bv, Wo, Wsc, Wpm, Wpv,
      Abf, Wt3, Wot, bqkv, scalar, mem, val, gbits, sbits);

  // merged QKV GEMM: M=24576, K=1024, N=1536 (writes Cm q|k + vT transposed)
  gemm128<1, 12><<<dim3(2304), dim3(256), 0, stream>>>(
      Abf, 1024, Wt3, 1024, bqkv, Cm, vT, nullptr);

  // DFT branch adds into q channels [0,256)
  dft2<<<dim3(Mrows / 32), dim3(256), 0, stream>>>(scalar, Wwq, mem, val, Cm);

  // flash attention (128 q-rows per block, K/V double-buffered)
  attn4<<<dim3(1536), dim3(256), 0, stream>>>(Cm, vT, gbits, sbits, mergedb);

  // output FC: M=24576, K=512, N=512, f32 out
  gemm128<0, 4><<<dim3(768), dim3(256), 0, stream>>>(
      mergedb, 512, Wot, 512, bo, nullptr, nullptr, out);
}

// Round 7
// 240.716 us; speedup vs baseline: 1.2153x; 1.0562x over previous
//
#include <hip/hip_runtime.h>
#include <hip/hip_bf16.h>
#include <cstdint>

// Problem constants
#define Tn 12
#define Nn 512
#define WIN 12
#define DFT 256
#define Pn 16
#define Mrows 24576
#define QSCALE 0.18033688011112042f   // log2(e)/8, folded into q at GEMM epilogue
#define DEFER_THR 11.541560327111707f // 8*log2(e)

typedef unsigned long long u64;
typedef __attribute__((ext_vector_type(8))) short short8;
typedef __attribute__((ext_vector_type(4))) float f32x4;
typedef __attribute__((address_space(1))) const void* gas1;
typedef __attribute__((address_space(3))) void* las3;

static __device__ __forceinline__ void gld16(const void* g, void* l) {
  __builtin_amdgcn_global_load_lds((gas1)g, (las3)l, 16, 0, 0);
}
static __device__ __forceinline__ short f2bf(float x) {
  __hip_bfloat16 h = __float2bfloat16(x);
  return *reinterpret_cast<short*>(&h);
}
static __device__ __forceinline__ float bf2f(short s) {
  __hip_bfloat16 h;
  *reinterpret_cast<short*>(&h) = s;
  return __bfloat162float(h);
}
static __device__ __forceinline__ f32x4 mfma16(short8 a, short8 b, f32x4 c) {
  return __builtin_amdgcn_mfma_f32_16x16x32_bf16(a, b, c, 0, 0, 0);
}
#if __has_builtin(__builtin_amdgcn_exp2f)
#define EXP2F(x) __builtin_amdgcn_exp2f(x)
#else
#define EXP2F(x) __expf((x) * 0.6931471805599453f)
#endif

// =============== fused prep: all pre-GEMM work in ONE launch ===============
// [0,6144): X|STE cast + fused scalar   [6144,8192): mask bit-pack
// [8192,8640): LDS-tiled weight transpose-cast  [8640,8646): bias concat
// [8646,8662): mem/val
__global__ __launch_bounds__(256) void prep_all(
    const float* __restrict__ X, const float* __restrict__ STE,
    const int* __restrict__ geo, const int* __restrict__ sem,
    const float* __restrict__ PK,
    const float* __restrict__ Wq, const float* __restrict__ bq,
    const float* __restrict__ Wk, const float* __restrict__ bk,
    const float* __restrict__ Wv, const float* __restrict__ bv,
    const float* __restrict__ Wo, const float* __restrict__ Wsc,
    const float* __restrict__ Wpm, const float* __restrict__ Wpv,
    short* __restrict__ Abf, short* __restrict__ Wt3, short* __restrict__ Wot,
    float* __restrict__ bqkv, float* __restrict__ scalar,
    float* __restrict__ mem, float* __restrict__ val,
    u64* __restrict__ gbits, u64* __restrict__ sbits) {
  __shared__ float tl[64][65];   // only used by transpose branch
  const int bid = blockIdx.x, tid = threadIdx.x;
  if (bid < 6144) {                              // X|STE cast + fused scalar
    const int lane = tid & 63, w = tid >> 6;
    const int m = bid * 4 + w;
    const int c8 = lane * 8;
    const float4 x0 = *reinterpret_cast<const float4*>(&X[(size_t)m * 512 + c8]);
    const float4 x1 = *reinterpret_cast<const float4*>(&X[(size_t)m * 512 + c8 + 4]);
    short8 xo;
    xo[0]=f2bf(x0.x); xo[1]=f2bf(x0.y); xo[2]=f2bf(x0.z); xo[3]=f2bf(x0.w);
    xo[4]=f2bf(x1.x); xo[5]=f2bf(x1.y); xo[6]=f2bf(x1.z); xo[7]=f2bf(x1.w);
    *reinterpret_cast<short8*>(&Abf[(size_t)m * 1024 + c8]) = xo;
    const float4 s0 = *reinterpret_cast<const float4*>(&STE[(size_t)m * 512 + c8]);
    const float4 s1 = *reinterpret_cast<const float4*>(&STE[(size_t)m * 512 + c8 + 4]);
    short8 so;
    so[0]=f2bf(s0.x); so[1]=f2bf(s0.y); so[2]=f2bf(s0.z); so[3]=f2bf(s0.w);
    so[4]=f2bf(s1.x); so[5]=f2bf(s1.y); so[6]=f2bf(s1.z); so[7]=f2bf(s1.w);
    *reinterpret_cast<short8*>(&Abf[(size_t)m * 1024 + 512 + c8]) = so;
    const float4 w0 = *reinterpret_cast<const float4*>(&Wsc[c8]);
    const float4 w1 = *reinterpret_cast<const float4*>(&Wsc[c8 + 4]);
    float d = x0.x*w0.x + x0.y*w0.y + x0.z*w0.z + x0.w*w0.w
            + x1.x*w1.x + x1.y*w1.y + x1.z*w1.z + x1.w*w1.w;
#pragma unroll
    for (int off = 32; off; off >>= 1) d += __shfl_xor(d, off);
    if (lane == 0) scalar[m] = d;
  } else if (bid < 8192) {                       // mask bit-pack
    const int pb = bid - 6144;                   // 0..2047
    const int which = pb >> 10, blk = pb & 1023;
    const int lane = tid & 63;
    const int unit = blk * 4 + (tid >> 6);       // 0..4095
    const int n = unit >> 3, seg = unit & 7;
    const int* __restrict__ src = which ? sem : geo;
    u64* __restrict__ dst = which ? sbits : gbits;
    const u64 word = __ballot(src[(size_t)n * 512 + seg * 64 + lane] != 0);
    if (lane == 0) dst[(size_t)n * 8 + seg] = word;
  } else if (bid < 8640) {                       // tiled weight transpose-cast
    const int ti0 = bid - 8192;                  // 0..447
    const float* W;
    short* out;
    int kt, nt, ldk;
    if (ti0 < 384) {
      const int mi = ti0 / 128, ti = ti0 % 128;
      W = (mi == 0) ? Wq : ((mi == 1) ? Wk : Wv);
      out = Wt3 + (size_t)mi * 512 * 1024;
      kt = ti >> 3; nt = ti & 7; ldk = 1024;     // W is 1024x512
    } else {
      const int ti = ti0 - 384;
      W = Wo; out = Wot;
      kt = ti >> 3; nt = ti & 7; ldk = 512;      // W is 512x512
    }
    const int k0 = kt * 64, n0 = nt * 64;
    {
      const int r = tid >> 2, c0 = (tid & 3) * 16;
#pragma unroll
      for (int u = 0; u < 4; ++u) {
        const float4 v = *reinterpret_cast<const float4*>(
            &W[(size_t)(k0 + r) * 512 + n0 + c0 + u * 4]);
        tl[r][c0+u*4+0]=v.x; tl[r][c0+u*4+1]=v.y; tl[r][c0+u*4+2]=v.z; tl[r][c0+u*4+3]=v.w;
      }
    }
    __syncthreads();
    {
      const int nn = tid >> 2, c0 = (tid & 3) * 16;
      short8 o0, o1;
#pragma unroll
      for (int u = 0; u < 8; ++u) o0[u] = f2bf(tl[c0 + u][nn]);
#pragma unroll
      for (int u = 0; u < 8; ++u) o1[u] = f2bf(tl[c0 + 8 + u][nn]);
      *reinterpret_cast<short8*>(&out[(size_t)(n0 + nn) * ldk + k0 + c0]) = o0;
      *reinterpret_cast<short8*>(&out[(size_t)(n0 + nn) * ldk + k0 + c0 + 8]) = o1;
    }
  } else if (bid < 8646) {                       // bias concat
    const int i = (bid - 8640) * 256 + tid;
    bqkv[i] = (i < 512) ? bq[i] : ((i < 1024) ? bk[i - 512] : bv[i - 1024]);
  } else {                                       // mem/val = PK @ Wpm/Wpv
    const int p = bid - 8646, f = tid;
    float m = 0.f, v = 0.f;
#pragma unroll
    for (int i = 0; i < WIN; ++i) {
      const float pk = PK[p * WIN + i];
      m += pk * Wpm[i * DFT + f];
      v += pk * Wpv[i * DFT + f];
    }
    mem[p * DFT + f] = m;
    val[p * DFT + f] = v;
  }
}

// ---------------- 128x128 MFMA GEMM, global_load_lds + XOR swizzle ----------------
// MODE 1: A[M x 1024] -> Cbf [M][1024] (cols<1024, relu bf16; q-cols scaled) and
//         vT[512][M] (cols>=1024, transposed)
// MODE 0: A[M x 512]  -> Cf  [M][512]  relu f32
template <int MODE, int NCB>
__global__ __launch_bounds__(256) void gemm128(
    const short* __restrict__ A, int lda,
    const short* __restrict__ Wt, int Ktot,
    const float* __restrict__ bias,
    short* __restrict__ Cbf, short* __restrict__ vT,
    float* __restrict__ Cf) {
  __shared__ alignas(16) short As[128 * 64];
  __shared__ alignas(16) short Bs[128 * 64];
  const int tid = threadIdx.x, lane = tid & 63, w = tid >> 6;
  const int wm = w >> 1, wn = w & 1, lg = lane >> 4, lc = lane & 15;
  const int L = blockIdx.x;
  const int x = L & 7, j = L >> 3;
  const int rp = x * 24 + j / NCB, cb = j - (j / NCB) * NCB;
  const int row0 = rp * 128, col0 = cb * 128;
  f32x4 acc[4][4];
#pragma unroll
  for (int i = 0; i < 4; ++i)
#pragma unroll
    for (int jj = 0; jj < 4; ++jj) acc[i][jj] = (f32x4){0.f, 0.f, 0.f, 0.f};

  for (int k0 = 0; k0 < Ktot; k0 += 64) {
    __syncthreads();
#pragma unroll
    for (int c = 0; c < 4; ++c) {
      const int slot0 = w * 256 + c * 64;
      const int slot = slot0 + lane;
      const int r = slot >> 3, gs = slot & 7, g = gs ^ (r & 7);
      gld16(&A[(size_t)(row0 + r) * lda + k0 + g * 8], &As[slot0 * 8]);
      gld16(&Wt[(size_t)(col0 + r) * Ktot + k0 + g * 8], &Bs[slot0 * 8]);
    }
    __syncthreads();
#pragma unroll
    for (int kh = 0; kh < 2; ++kh) {
      short8 b[4];
#pragma unroll
      for (int ns = 0; ns < 4; ++ns) {
        const int rb = wn * 64 + ns * 16 + lc;
        b[ns] = *reinterpret_cast<const short8*>(
            &Bs[(rb * 8 + ((kh * 4 + lg) ^ (rb & 7))) * 8]);
      }
#pragma unroll
      for (int ms = 0; ms < 4; ++ms) {
        const int ra = wm * 64 + ms * 16 + lc;
        const short8 a = *reinterpret_cast<const short8*>(
            &As[(ra * 8 + ((kh * 4 + lg) ^ (ra & 7))) * 8]);
#pragma unroll
        for (int ns = 0; ns < 4; ++ns) acc[ms][ns] = mfma16(a, b[ns], acc[ms][ns]);
      }
    }
  }
  // epilogue
#pragma unroll
  for (int ms = 0; ms < 4; ++ms) {
    const int rowb = row0 + wm * 64 + ms * 16 + lg * 4;
#pragma unroll
    for (int ns = 0; ns < 4; ++ns) {
      const int colg = col0 + wn * 64 + ns * 16 + lc;
      const float bv = bias[colg];
      if constexpr (MODE == 0) {
#pragma unroll
        for (int r = 0; r < 4; ++r) {
          float vv = acc[ms][ns][r] + bv;
          Cf[(size_t)(rowb + r) * 512 + colg] = vv > 0.f ? vv : 0.f;
        }
      } else {
        if (colg < 1024) {
          const float sc = (colg < 512) ? QSCALE : 1.f;  // pre-scale q for softmax
#pragma unroll
          for (int r = 0; r < 4; ++r) {
            float vv = acc[ms][ns][r] + bv;
            vv = vv > 0.f ? vv : 0.f;
            Cbf[(size_t)(rowb + r) * 1024 + colg] = f2bf(vv * sc);
          }
        } else {
          short4 t4;
          float vv0 = acc[ms][ns][0] + bv; t4.x = f2bf(vv0 > 0.f ? vv0 : 0.f);
          float vv1 = acc[ms][ns][1] + bv; t4.y = f2bf(vv1 > 0.f ? vv1 : 0.f);
          float vv2 = acc[ms][ns][2] + bv; t4.z = f2bf(vv2 > 0.f ? vv2 : 0.f);
          float vv3 = acc[ms][ns][3] + bv; t4.w = f2bf(vv3 > 0.f ? vv3 : 0.f);
          *reinterpret_cast<short4*>(&vT[(size_t)(colg - 1024) * Mrows + rowb]) = t4;
        }
      }
    }
  }
}

// ---- DFT branch v2: wave-parallel; output pre-scaled by QSCALE via vall ----
__global__ __launch_bounds__(256) void dft2(
    const float* __restrict__ scalar, const float* __restrict__ Wwq,
    const float* __restrict__ mem, const float* __restrict__ val,
    short* __restrict__ q) {
  __shared__ float wwql[12][256];
  __shared__ float meml[16][260];
  __shared__ float vall[16][260];
  __shared__ float qdl[4][256];
  const int tid = threadIdx.x, lane = tid & 63, w = tid >> 6;
  for (int i = tid; i < 3072; i += 256) wwql[0][i] = Wwq[i];   // [12][256] flat
  for (int i = tid; i < 4096; i += 256) {
    meml[i >> 8][i & 255] = mem[i];
    vall[i >> 8][i & 255] = val[i] * QSCALE;   // fold softmax pre-scale
  }
  __syncthreads();
  const int mrow0 = blockIdx.x * 32;
  const int bt = mrow0 >> 9;      // 32 rows stay within one bt (512-aligned)
  const int t = bt % Tn;
  const int p = lane & 15, sg = lane >> 4;
#pragma unroll 1
  for (int it = 0; it < 8; ++it) {
    const int mrow = mrow0 + w * 8 + it;
    const int n = mrow & 511;
    float wl[12];
#pragma unroll
    for (int i = 0; i < 12; ++i) {
      const int ti = t + i - (WIN - 1);
      wl[i] = (ti >= 0) ? scalar[(size_t)(bt + i - (WIN - 1)) * Nn + n] : 0.f;
    }
    float4 qd = {0.f, 0.f, 0.f, 0.f};
#pragma unroll
    for (int i = 0; i < 12; ++i) {
      const float4 wv = *reinterpret_cast<const float4*>(&wwql[i][lane * 4]);
      qd.x += wl[i] * wv.x; qd.y += wl[i] * wv.y;
      qd.z += wl[i] * wv.z; qd.w += wl[i] * wv.w;
    }
    *reinterpret_cast<float4*>(&qdl[w][lane * 4]) = qd;
    asm volatile("s_waitcnt lgkmcnt(0)" ::: "memory");
    float ps = 0.f;
#pragma unroll
    for (int ff = 0; ff < 16; ++ff) {
      const float4 qv = *reinterpret_cast<const float4*>(&qdl[w][sg * 64 + ff * 4]);
      const float4 mv = *reinterpret_cast<const float4*>(&meml[p][sg * 64 + ff * 4]);
      ps += qv.x * mv.x + qv.y * mv.y + qv.z * mv.z + qv.w * mv.w;
    }
    ps += __shfl_xor(ps, 16);
    ps += __shfl_xor(ps, 32);
    const float s = ps * 0.0625f;
    float mx = s;
#pragma unroll
    for (int off = 1; off < 16; off <<= 1) mx = fmaxf(mx, __shfl_xor(mx, off));
    const float e = __expf(s - mx);
    float den = e;
#pragma unroll
    for (int off = 1; off < 16; off <<= 1) den += __shfl_xor(den, off);
    const float a = e / den;
    float4 o = {0.f, 0.f, 0.f, 0.f};
#pragma unroll
    for (int pp = 0; pp < 16; ++pp) {
      const float ap = __shfl(a, pp);
      const float4 vv = *reinterpret_cast<const float4*>(&vall[pp][lane * 4]);
      o.x += ap * vv.x; o.y += ap * vv.y; o.z += ap * vv.z; o.w += ap * vv.w;
    }
    const size_t qi = (size_t)mrow * 1024 + lane * 4;
    short4 qo = *reinterpret_cast<const short4*>(&q[qi]);
    short4 qn;
    qn.x = f2bf(bf2f(qo.x) + o.x);
    qn.y = f2bf(bf2f(qo.y) + o.y);
    qn.z = f2bf(bf2f(qo.z) + o.z);
    qn.w = f2bf(bf2f(qo.w) + o.w);
    *reinterpret_cast<short4*>(&q[qi]) = qn;
  }
}

// ---- MFMA flash attention v4b: dbuf staging + exp2 softmax + defer-max ----
#define ASTAGE(B, CH) { \
  _Pragma("unroll") for (int c = 0; c < 2; ++c) { \
    const int slot0 = (w * 2 + c) * 64; \
    const int slot = slot0 + lane; \
    const int r = slot >> 3, gs = slot & 7, gg = gs ^ (r & 7); \
    gld16(&Cm[(rowbase + (CH) * 64 + r) * 1024 + kcol + gg * 8], &Klds[B][slot0 * 8]); \
    gld16(&vT[(size_t)(vrow0 + r) * Mrows + rowbase + (CH) * 64 + gg * 8], \
          &Vlds[B][slot0 * 8]); } }

__global__ __launch_bounds__(256) void attn4(
    const short* __restrict__ Cm, const short* __restrict__ vT,
    const u64* __restrict__ gbits, const u64* __restrict__ sbits,
    short* __restrict__ merged) {
  const int L = blockIdx.x;            // 0..1535
  const int x = L & 7, j = L >> 3;     // j 0..191
  const int g = x * 48 + (j >> 2);     // same (head,bt) -> same XCD
  const int qt = j & 3;
  const int head = g & 7, bt = g >> 3;
  const u64* __restrict__ bits = (head < 4) ? gbits : sbits;
  const int tid = threadIdx.x, lane = tid & 63, w = tid >> 6;
  const int lg = lane >> 4, qc = lane & 15;
  const size_t rowbase = (size_t)bt * 512;
  const int n0 = qt * 128;
  const int qcol = head * 64, kcol = 512 + head * 64, vrow0 = head * 64;

  __shared__ alignas(16) short Klds[2][4096];
  __shared__ alignas(16) short Vlds[2][4096];
  __shared__ alignas(16) short Plds[4][2][16][72];

  short8 qf[2][2];
  int qrow[2];
#pragma unroll
  for (int qs = 0; qs < 2; ++qs) {
    qrow[qs] = n0 + w * 32 + qs * 16 + qc;
    qf[qs][0] = *reinterpret_cast<const short8*>(
        &Cm[(rowbase + qrow[qs]) * 1024 + qcol + lg * 8]);
    qf[qs][1] = *reinterpret_cast<const short8*>(
        &Cm[(rowbase + qrow[qs]) * 1024 + qcol + 32 + lg * 8]);
  }

  float m_run[2] = {-1e28f, -1e28f}, l_run[2] = {0.f, 0.f};
  f32x4 o[2][4];
#pragma unroll
  for (int qs = 0; qs < 2; ++qs)
#pragma unroll
    for (int i = 0; i < 4; ++i) o[qs][i] = (f32x4){0.f, 0.f, 0.f, 0.f};

  ASTAGE(0, 0);
  u64 mw0 = bits[(size_t)(n0 + w * 32 + qc) * 8];
  u64 mw1 = bits[(size_t)(n0 + w * 32 + 16 + qc) * 8];
  asm volatile("s_waitcnt vmcnt(0)" ::: "memory");
  __syncthreads();

  int cur = 0;
#pragma unroll 1
  for (int ch = 0; ch < 8; ++ch) {
    if (ch < 7) ASTAGE(cur ^ 1, ch + 1);            // prefetch next chunk
    u64 nmw0 = 0, nmw1 = 0;
    if (ch < 7) {                                    // prefetch next masks
      nmw0 = bits[(size_t)(n0 + w * 32 + qc) * 8 + ch + 1];
      nmw1 = bits[(size_t)(n0 + w * 32 + 16 + qc) * 8 + ch + 1];
    }
    // S^T = K . Q^T (scores arrive pre-scaled by log2e/8 via q)
    float p[2][4][4];
    float cm0 = -1e30f, cm1 = -1e30f;
#pragma unroll
    for (int s = 0; s < 4; ++s) {
      const int rk = s * 16 + qc;
      const short8 a0 = *reinterpret_cast<const short8*>(
          &Klds[cur][(rk * 8 + (lg ^ (rk & 7))) * 8]);
      const short8 a1 = *reinterpret_cast<const short8*>(
          &Klds[cur][(rk * 8 + ((4 + lg) ^ (rk & 7))) * 8]);
      f32x4 sa0 = (f32x4){0.f, 0.f, 0.f, 0.f};
      f32x4 sa1 = (f32x4){0.f, 0.f, 0.f, 0.f};
      __builtin_amdgcn_s_setprio(1);
      sa0 = mfma16(a0, qf[0][0], sa0);
      sa0 = mfma16(a1, qf[0][1], sa0);
      sa1 = mfma16(a0, qf[1][0], sa1);
      sa1 = mfma16(a1, qf[1][1], sa1);
      __builtin_amdgcn_s_setprio(0);
#pragma unroll
      for (int r = 0; r < 4; ++r) {
        const int kb = s * 16 + lg * 4 + r;
        const float sv0 = ((mw0 >> kb) & 1ull) ? sa0[r] : -1e30f;
        const float sv1 = ((mw1 >> kb) & 1ull) ? sa1[r] : -1e30f;
        p[0][s][r] = sv0; cm0 = fmaxf(cm0, sv0);
        p[1][s][r] = sv1; cm1 = fmaxf(cm1, sv1);
      }
    }
    float cms[2] = {cm0, cm1};
#pragma unroll
    for (int qs = 0; qs < 2; ++qs) {
      float cm = cms[qs];
      cm = fmaxf(cm, __shfl_xor(cm, 16));
      cm = fmaxf(cm, __shfl_xor(cm, 32));
      if (!__all(cm - m_run[qs] <= DEFER_THR)) {     // T13 defer-max
        const float m_new = fmaxf(m_run[qs], cm);
        const float alpha = EXP2F(m_run[qs] - m_new);
        l_run[qs] *= alpha;
#pragma unroll
        for (int i = 0; i < 4; ++i) o[qs][i] *= alpha;
        m_run[qs] = m_new;
      }
      const float mr = m_run[qs];
      float csum = 0.f;
#pragma unroll
      for (int s = 0; s < 4; ++s) {
        short4 p4;
        const float pv0 = EXP2F(p[qs][s][0] - mr);   // masked: exp2(-1e30-mr)=0
        const float pv1 = EXP2F(p[qs][s][1] - mr);
        const float pv2 = EXP2F(p[qs][s][2] - mr);
        const float pv3 = EXP2F(p[qs][s][3] - mr);
        csum += pv0 + pv1 + pv2 + pv3;
        p4.x = f2bf(pv0); p4.y = f2bf(pv1); p4.z = f2bf(pv2); p4.w = f2bf(pv3);
        *reinterpret_cast<short4*>(&Plds[w][qs][qc][s * 16 + lg * 4]) = p4;
      }
      csum += __shfl_xor(csum, 16);
      csum += __shfl_xor(csum, 32);
      l_run[qs] += csum;
    }

    // O^T += V^T . P^T, V fragments shared across q-subtiles
#pragma unroll
    for (int kh = 0; kh < 2; ++kh) {
      const short8 pb0 = *reinterpret_cast<const short8*>(
          &Plds[w][0][qc][kh * 32 + lg * 8]);
      const short8 pb1 = *reinterpret_cast<const short8*>(
          &Plds[w][1][qc][kh * 32 + lg * 8]);
      __builtin_amdgcn_s_setprio(1);
#pragma unroll
      for (int ds = 0; ds < 4; ++ds) {
        const int rd = ds * 16 + qc;
        const short8 va = *reinterpret_cast<const short8*>(
            &Vlds[cur][(rd * 8 + ((kh * 4 + lg) ^ (rd & 7))) * 8]);
        o[0][ds] = mfma16(va, pb0, o[0][ds]);
        o[1][ds] = mfma16(va, pb1, o[1][ds]);
      }
      __builtin_amdgcn_s_setprio(0);
    }
    asm volatile("s_waitcnt vmcnt(0)" ::: "memory");   // next chunk landed
    __syncthreads();                                    // all waves done with cur
    cur ^= 1;
    mw0 = nmw0; mw1 = nmw1;
  }
#pragma unroll
  for (int qs = 0; qs < 2; ++qs) {
    const float inv = l_run[qs] > 0.f ? 1.f / l_run[qs] : 0.f;
#pragma unroll
    for (int ds = 0; ds < 4; ++ds) {
      short4 t4;
      t4.x = f2bf(o[qs][ds][0] * inv);
      t4.y = f2bf(o[qs][ds][1] * inv);
      t4.z = f2bf(o[qs][ds][2] * inv);
      t4.w = f2bf(o[qs][ds][3] * inv);
      *reinterpret_cast<short4*>(
          &merged[(rowbase + qrow[qs]) * 512 + head * 64 + ds * 16 + lg * 4]) = t4;
    }
  }
}

// ---------------- launch ----------------
extern "C" void kernel_launch(void* const* d_in, const int* in_sizes, int n_in,
                              void* d_out, int out_size, void* d_ws, size_t ws_size,
                              hipStream_t stream) {
  const float* X        = (const float*)d_in[0];
  const float* STE      = (const float*)d_in[1];
  const int*   geo_mask = (const int*)d_in[2];
  const int*   sem_mask = (const int*)d_in[3];
  const float* PK       = (const float*)d_in[4];
  const float* Wq       = (const float*)d_in[5];
  const float* bq       = (const float*)d_in[6];
  const float* Wk       = (const float*)d_in[7];
  const float* bk       = (const float*)d_in[8];
  const float* Wv       = (const float*)d_in[9];
  const float* bv       = (const float*)d_in[10];
  const float* Wo       = (const float*)d_in[11];
  const float* bo       = (const float*)d_in[12];
  const float* Wsc      = (const float*)d_in[13];
  const float* Wwq      = (const float*)d_in[14];
  const float* Wpm      = (const float*)d_in[15];
  const float* Wpv      = (const float*)d_in[16];
  float* out = (float*)d_out;

  char* wsb = (char*)d_ws;
  short* Abf     = (short*)(wsb);                    // 24576x1024 bf16
  short* mergedb = (short*)(wsb);                    // aliases Abf (dead after QKV)
  short* Cm      = (short*)(wsb + 50331648);         // 24576x1024 bf16: q|k
  short* vT      = (short*)(wsb + 100663296);        // 512x24576 bf16
  short* Wt3     = (short*)(wsb + 125829120);        // 1536x1024 bf16
  short* Wot     = (short*)(wsb + 128974848);        // 512x512 bf16
  float* bqkv    = (float*)(wsb + 129499136);        // 1536 f32
  float* scalar  = (float*)(wsb + 129505280);        // 24576 f32
  float* mem     = (float*)(wsb + 129603584);
  float* val     = (float*)(wsb + 129619968);
  u64*   gbits   = (u64*)  (wsb + 129636352);
  u64*   sbits   = (u64*)  (wsb + 129669120);

  // all prep in one launch (cast+scalar | masks | tiled W transpose | bias | mem/val)
  prep_all<<<dim3(8662), dim3(256), 0, stream>>>(
      X, STE, geo_mask, sem_mask, PK, Wq, bq, Wk, bk, Wv, bv, Wo, Wsc, Wpm, Wpv,
      Abf, Wt3, Wot, bqkv, scalar, mem, val, gbits, sbits);

  // merged QKV GEMM: M=24576, K=1024, N=1536 (writes Cm q|k + vT transposed)
  gemm128<1, 12><<<dim3(2304), dim3(256), 0, stream>>>(
      Abf, 1024, Wt3, 1024, bqkv, Cm, vT, nullptr);

  // DFT branch adds into q channels [0,256)
  dft2<<<dim3(Mrows / 32), dim3(256), 0, stream>>>(scalar, Wwq, mem, val, Cm);

  // flash attention (128 q-rows per block, K/V double-buffered, exp2 softmax)
  attn4<<<dim3(1536), dim3(256), 0, stream>>>(Cm, vT, gbits, sbits, mergedb);

  // output FC: M=24576, K=512, N=512, f32 out
  gemm128<0, 4><<<dim3(768), dim3(256), 0, stream>>>(
      mergedb, 512, Wot, 512, bo, nullptr, nullptr, out);
}

// Round 8
// 226.830 us; speedup vs baseline: 1.2897x; 1.0612x over previous
//
#include <hip/hip_runtime.h>
#include <hip/hip_bf16.h>
#include <cstdint>

// Problem constants
#define Tn 12
#define Nn 512
#define WIN 12
#define DFT 256
#define Pn 16
#define Mrows 24576
#define QSCALE 0.18033688011112042f   // log2(e)/8, folded into q at GEMM epilogue
#define M0F 16.0f                     // fixed softmax reference (scores bounded)

typedef unsigned long long u64;
typedef __attribute__((ext_vector_type(8))) short short8;
typedef __attribute__((ext_vector_type(4))) float f32x4;
typedef __attribute__((address_space(1))) const void* gas1;
typedef __attribute__((address_space(3))) void* las3;

static __device__ __forceinline__ void gld16(const void* g, void* l) {
  __builtin_amdgcn_global_load_lds((gas1)g, (las3)l, 16, 0, 0);
}
static __device__ __forceinline__ short f2bf(float x) {
  __hip_bfloat16 h = __float2bfloat16(x);
  return *reinterpret_cast<short*>(&h);
}
static __device__ __forceinline__ float bf2f(short s) {
  __hip_bfloat16 h;
  *reinterpret_cast<short*>(&h) = s;
  return __bfloat162float(h);
}
static __device__ __forceinline__ f32x4 mfma16(short8 a, short8 b, f32x4 c) {
  return __builtin_amdgcn_mfma_f32_16x16x32_bf16(a, b, c, 0, 0, 0);
}
#if __has_builtin(__builtin_amdgcn_exp2f)
#define EXP2F(x) __builtin_amdgcn_exp2f(x)
#else
#define EXP2F(x) __expf((x) * 0.6931471805599453f)
#endif

// =============== fused prep: all pre-GEMM work in ONE launch ===============
// [0,6144): X|STE cast + fused scalar   [6144,8192): mask bit-pack
// [8192,8640): LDS-tiled weight transpose-cast  [8640,8646): bias concat
// [8646,8662): mem/val
__global__ __launch_bounds__(256) void prep_all(
    const float* __restrict__ X, const float* __restrict__ STE,
    const int* __restrict__ geo, const int* __restrict__ sem,
    const float* __restrict__ PK,
    const float* __restrict__ Wq, const float* __restrict__ bq,
    const float* __restrict__ Wk, const float* __restrict__ bk,
    const float* __restrict__ Wv, const float* __restrict__ bv,
    const float* __restrict__ Wo, const float* __restrict__ Wsc,
    const float* __restrict__ Wpm, const float* __restrict__ Wpv,
    short* __restrict__ Abf, short* __restrict__ Wt3, short* __restrict__ Wot,
    float* __restrict__ bqkv, float* __restrict__ scalar,
    float* __restrict__ mem, float* __restrict__ val,
    u64* __restrict__ gbits, u64* __restrict__ sbits) {
  __shared__ float tl[64][65];   // only used by transpose branch
  const int bid = blockIdx.x, tid = threadIdx.x;
  if (bid < 6144) {                              // X|STE cast + fused scalar
    const int lane = tid & 63, w = tid >> 6;
    const int m = bid * 4 + w;
    const int c8 = lane * 8;
    const float4 x0 = *reinterpret_cast<const float4*>(&X[(size_t)m * 512 + c8]);
    const float4 x1 = *reinterpret_cast<const float4*>(&X[(size_t)m * 512 + c8 + 4]);
    short8 xo;
    xo[0]=f2bf(x0.x); xo[1]=f2bf(x0.y); xo[2]=f2bf(x0.z); xo[3]=f2bf(x0.w);
    xo[4]=f2bf(x1.x); xo[5]=f2bf(x1.y); xo[6]=f2bf(x1.z); xo[7]=f2bf(x1.w);
    *reinterpret_cast<short8*>(&Abf[(size_t)m * 1024 + c8]) = xo;
    const float4 s0 = *reinterpret_cast<const float4*>(&STE[(size_t)m * 512 + c8]);
    const float4 s1 = *reinterpret_cast<const float4*>(&STE[(size_t)m * 512 + c8 + 4]);
    short8 so;
    so[0]=f2bf(s0.x); so[1]=f2bf(s0.y); so[2]=f2bf(s0.z); so[3]=f2bf(s0.w);
    so[4]=f2bf(s1.x); so[5]=f2bf(s1.y); so[6]=f2bf(s1.z); so[7]=f2bf(s1.w);
    *reinterpret_cast<short8*>(&Abf[(size_t)m * 1024 + 512 + c8]) = so;
    const float4 w0 = *reinterpret_cast<const float4*>(&Wsc[c8]);
    const float4 w1 = *reinterpret_cast<const float4*>(&Wsc[c8 + 4]);
    float d = x0.x*w0.x + x0.y*w0.y + x0.z*w0.z + x0.w*w0.w
            + x1.x*w1.x + x1.y*w1.y + x1.z*w1.z + x1.w*w1.w;
#pragma unroll
    for (int off = 32; off; off >>= 1) d += __shfl_xor(d, off);
    if (lane == 0) scalar[m] = d;
  } else if (bid < 8192) {                       // mask bit-pack
    const int pb = bid - 6144;                   // 0..2047
    const int which = pb >> 10, blk = pb & 1023;
    const int lane = tid & 63;
    const int unit = blk * 4 + (tid >> 6);       // 0..4095
    const int n = unit >> 3, seg = unit & 7;
    const int* __restrict__ src = which ? sem : geo;
    u64* __restrict__ dst = which ? sbits : gbits;
    const u64 word = __ballot(src[(size_t)n * 512 + seg * 64 + lane] != 0);
    if (lane == 0) dst[(size_t)n * 8 + seg] = word;
  } else if (bid < 8640) {                       // tiled weight transpose-cast
    const int ti0 = bid - 8192;                  // 0..447
    const float* W;
    short* out;
    int kt, nt, ldk;
    if (ti0 < 384) {
      const int mi = ti0 / 128, ti = ti0 % 128;
      W = (mi == 0) ? Wq : ((mi == 1) ? Wk : Wv);
      out = Wt3 + (size_t)mi * 512 * 1024;
      kt = ti >> 3; nt = ti & 7; ldk = 1024;     // W is 1024x512
    } else {
      const int ti = ti0 - 384;
      W = Wo; out = Wot;
      kt = ti >> 3; nt = ti & 7; ldk = 512;      // W is 512x512
    }
    const int k0 = kt * 64, n0 = nt * 64;
    {
      const int r = tid >> 2, c0 = (tid & 3) * 16;
#pragma unroll
      for (int u = 0; u < 4; ++u) {
        const float4 v = *reinterpret_cast<const float4*>(
            &W[(size_t)(k0 + r) * 512 + n0 + c0 + u * 4]);
        tl[r][c0+u*4+0]=v.x; tl[r][c0+u*4+1]=v.y; tl[r][c0+u*4+2]=v.z; tl[r][c0+u*4+3]=v.w;
      }
    }
    __syncthreads();
    {
      const int nn = tid >> 2, c0 = (tid & 3) * 16;
      short8 o0, o1;
#pragma unroll
      for (int u = 0; u < 8; ++u) o0[u] = f2bf(tl[c0 + u][nn]);
#pragma unroll
      for (int u = 0; u < 8; ++u) o1[u] = f2bf(tl[c0 + 8 + u][nn]);
      *reinterpret_cast<short8*>(&out[(size_t)(n0 + nn) * ldk + k0 + c0]) = o0;
      *reinterpret_cast<short8*>(&out[(size_t)(n0 + nn) * ldk + k0 + c0 + 8]) = o1;
    }
  } else if (bid < 8646) {                       // bias concat
    const int i = (bid - 8640) * 256 + tid;
    bqkv[i] = (i < 512) ? bq[i] : ((i < 1024) ? bk[i - 512] : bv[i - 1024]);
  } else {                                       // mem/val = PK @ Wpm/Wpv
    const int p = bid - 8646, f = tid;
    float m = 0.f, v = 0.f;
#pragma unroll
    for (int i = 0; i < WIN; ++i) {
      const float pk = PK[p * WIN + i];
      m += pk * Wpm[i * DFT + f];
      v += pk * Wpv[i * DFT + f];
    }
    mem[p * DFT + f] = m;
    val[p * DFT + f] = v;
  }
}

// ---------------- 128x128 MFMA GEMM, global_load_lds + XOR swizzle ----------------
// MODE 1: A[M x 1024] -> Cbf [M][1024] (cols<1024, relu bf16; q-cols scaled) and
//         vT[512][M] (cols>=1024, transposed)
// MODE 0: A[M x 512]  -> Cf  [M][512]  relu f32
template <int MODE, int NCB>
__global__ __launch_bounds__(256) void gemm128(
    const short* __restrict__ A, int lda,
    const short* __restrict__ Wt, int Ktot,
    const float* __restrict__ bias,
    short* __restrict__ Cbf, short* __restrict__ vT,
    float* __restrict__ Cf) {
  __shared__ alignas(16) short As[128 * 64];
  __shared__ alignas(16) short Bs[128 * 64];
  const int tid = threadIdx.x, lane = tid & 63, w = tid >> 6;
  const int wm = w >> 1, wn = w & 1, lg = lane >> 4, lc = lane & 15;
  const int L = blockIdx.x;
  const int x = L & 7, j = L >> 3;
  const int rp = x * 24 + j / NCB, cb = j - (j / NCB) * NCB;
  const int row0 = rp * 128, col0 = cb * 128;
  f32x4 acc[4][4];
#pragma unroll
  for (int i = 0; i < 4; ++i)
#pragma unroll
    for (int jj = 0; jj < 4; ++jj) acc[i][jj] = (f32x4){0.f, 0.f, 0.f, 0.f};

  for (int k0 = 0; k0 < Ktot; k0 += 64) {
    __syncthreads();
#pragma unroll
    for (int c = 0; c < 4; ++c) {
      const int slot0 = w * 256 + c * 64;
      const int slot = slot0 + lane;
      const int r = slot >> 3, gs = slot & 7, g = gs ^ (r & 7);
      gld16(&A[(size_t)(row0 + r) * lda + k0 + g * 8], &As[slot0 * 8]);
      gld16(&Wt[(size_t)(col0 + r) * Ktot + k0 + g * 8], &Bs[slot0 * 8]);
    }
    __syncthreads();
#pragma unroll
    for (int kh = 0; kh < 2; ++kh) {
      short8 b[4];
#pragma unroll
      for (int ns = 0; ns < 4; ++ns) {
        const int rb = wn * 64 + ns * 16 + lc;
        b[ns] = *reinterpret_cast<const short8*>(
            &Bs[(rb * 8 + ((kh * 4 + lg) ^ (rb & 7))) * 8]);
      }
#pragma unroll
      for (int ms = 0; ms < 4; ++ms) {
        const int ra = wm * 64 + ms * 16 + lc;
        const short8 a = *reinterpret_cast<const short8*>(
            &As[(ra * 8 + ((kh * 4 + lg) ^ (ra & 7))) * 8]);
#pragma unroll
        for (int ns = 0; ns < 4; ++ns) acc[ms][ns] = mfma16(a, b[ns], acc[ms][ns]);
      }
    }
  }
  // epilogue
#pragma unroll
  for (int ms = 0; ms < 4; ++ms) {
    const int rowb = row0 + wm * 64 + ms * 16 + lg * 4;
#pragma unroll
    for (int ns = 0; ns < 4; ++ns) {
      const int colg = col0 + wn * 64 + ns * 16 + lc;
      const float bv = bias[colg];
      if constexpr (MODE == 0) {
#pragma unroll
        for (int r = 0; r < 4; ++r) {
          float vv = acc[ms][ns][r] + bv;
          Cf[(size_t)(rowb + r) * 512 + colg] = vv > 0.f ? vv : 0.f;
        }
      } else {
        if (colg < 1024) {
          const float sc = (colg < 512) ? QSCALE : 1.f;  // pre-scale q for softmax
#pragma unroll
          for (int r = 0; r < 4; ++r) {
            float vv = acc[ms][ns][r] + bv;
            vv = vv > 0.f ? vv : 0.f;
            Cbf[(size_t)(rowb + r) * 1024 + colg] = f2bf(vv * sc);
          }
        } else {
          short4 t4;
          float vv0 = acc[ms][ns][0] + bv; t4.x = f2bf(vv0 > 0.f ? vv0 : 0.f);
          float vv1 = acc[ms][ns][1] + bv; t4.y = f2bf(vv1 > 0.f ? vv1 : 0.f);
          float vv2 = acc[ms][ns][2] + bv; t4.z = f2bf(vv2 > 0.f ? vv2 : 0.f);
          float vv3 = acc[ms][ns][3] + bv; t4.w = f2bf(vv3 > 0.f ? vv3 : 0.f);
          *reinterpret_cast<short4*>(&vT[(size_t)(colg - 1024) * Mrows + rowb]) = t4;
        }
      }
    }
  }
}

// ---- DFT branch v2: wave-parallel; output pre-scaled by QSCALE via vall ----
__global__ __launch_bounds__(256) void dft2(
    const float* __restrict__ scalar, const float* __restrict__ Wwq,
    const float* __restrict__ mem, const float* __restrict__ val,
    short* __restrict__ q) {
  __shared__ float wwql[12][256];
  __shared__ float meml[16][260];
  __shared__ float vall[16][260];
  __shared__ float qdl[4][256];
  const int tid = threadIdx.x, lane = tid & 63, w = tid >> 6;
  for (int i = tid; i < 3072; i += 256) wwql[0][i] = Wwq[i];   // [12][256] flat
  for (int i = tid; i < 4096; i += 256) {
    meml[i >> 8][i & 255] = mem[i];
    vall[i >> 8][i & 255] = val[i] * QSCALE;   // fold softmax pre-scale
  }
  __syncthreads();
  const int mrow0 = blockIdx.x * 32;
  const int bt = mrow0 >> 9;      // 32 rows stay within one bt (512-aligned)
  const int t = bt % Tn;
  const int p = lane & 15, sg = lane >> 4;
#pragma unroll 1
  for (int it = 0; it < 8; ++it) {
    const int mrow = mrow0 + w * 8 + it;
    const int n = mrow & 511;
    float wl[12];
#pragma unroll
    for (int i = 0; i < 12; ++i) {
      const int ti = t + i - (WIN - 1);
      wl[i] = (ti >= 0) ? scalar[(size_t)(bt + i - (WIN - 1)) * Nn + n] : 0.f;
    }
    float4 qd = {0.f, 0.f, 0.f, 0.f};
#pragma unroll
    for (int i = 0; i < 12; ++i) {
      const float4 wv = *reinterpret_cast<const float4*>(&wwql[i][lane * 4]);
      qd.x += wl[i] * wv.x; qd.y += wl[i] * wv.y;
      qd.z += wl[i] * wv.z; qd.w += wl[i] * wv.w;
    }
    *reinterpret_cast<float4*>(&qdl[w][lane * 4]) = qd;
    asm volatile("s_waitcnt lgkmcnt(0)" ::: "memory");
    float ps = 0.f;
#pragma unroll
    for (int ff = 0; ff < 16; ++ff) {
      const float4 qv = *reinterpret_cast<const float4*>(&qdl[w][sg * 64 + ff * 4]);
      const float4 mv = *reinterpret_cast<const float4*>(&meml[p][sg * 64 + ff * 4]);
      ps += qv.x * mv.x + qv.y * mv.y + qv.z * mv.z + qv.w * mv.w;
    }
    ps += __shfl_xor(ps, 16);
    ps += __shfl_xor(ps, 32);
    const float s = ps * 0.0625f;
    float mx = s;
#pragma unroll
    for (int off = 1; off < 16; off <<= 1) mx = fmaxf(mx, __shfl_xor(mx, off));
    const float e = __expf(s - mx);
    float den = e;
#pragma unroll
    for (int off = 1; off < 16; off <<= 1) den += __shfl_xor(den, off);
    const float a = e / den;
    float4 o = {0.f, 0.f, 0.f, 0.f};
#pragma unroll
    for (int pp = 0; pp < 16; ++pp) {
      const float ap = __shfl(a, pp);
      const float4 vv = *reinterpret_cast<const float4*>(&vall[pp][lane * 4]);
      o.x += ap * vv.x; o.y += ap * vv.y; o.z += ap * vv.z; o.w += ap * vv.w;
    }
    const size_t qi = (size_t)mrow * 1024 + lane * 4;
    short4 qo = *reinterpret_cast<const short4*>(&q[qi]);
    short4 qn;
    qn.x = f2bf(bf2f(qo.x) + o.x);
    qn.y = f2bf(bf2f(qo.y) + o.y);
    qn.z = f2bf(bf2f(qo.z) + o.z);
    qn.w = f2bf(bf2f(qo.w) + o.w);
    *reinterpret_cast<short4*>(&q[qi]) = qn;
  }
}

// ---- MFMA flash attention v5: dbuf + fixed-reference softmax (no max pass) ----
// Scores s = log2e/8 * <q,k> - 16 (via MFMA C-init) are bounded; P = exp2(s),
// normalized by running sum. No max tracking, no rescale, no defer logic.
#define ASTAGE(B, CH) { \
  _Pragma("unroll") for (int c = 0; c < 2; ++c) { \
    const int slot0 = (w * 2 + c) * 64; \
    const int slot = slot0 + lane; \
    const int r = slot >> 3, gs = slot & 7, gg = gs ^ (r & 7); \
    gld16(&Cm[(rowbase + (CH) * 64 + r) * 1024 + kcol + gg * 8], &Klds[B][slot0 * 8]); \
    gld16(&vT[(size_t)(vrow0 + r) * Mrows + rowbase + (CH) * 64 + gg * 8], \
          &Vlds[B][slot0 * 8]); } }

__global__ __launch_bounds__(256) void attn5(
    const short* __restrict__ Cm, const short* __restrict__ vT,
    const u64* __restrict__ gbits, const u64* __restrict__ sbits,
    short* __restrict__ merged) {
  const int L = blockIdx.x;            // 0..1535
  const int x = L & 7, j = L >> 3;     // j 0..191
  const int g = x * 48 + (j >> 2);     // same (head,bt) -> same XCD
  const int qt = j & 3;
  const int head = g & 7, bt = g >> 3;
  const u64* __restrict__ bits = (head < 4) ? gbits : sbits;
  const int tid = threadIdx.x, lane = tid & 63, w = tid >> 6;
  const int lg = lane >> 4, qc = lane & 15;
  const size_t rowbase = (size_t)bt * 512;
  const int n0 = qt * 128;
  const int qcol = head * 64, kcol = 512 + head * 64, vrow0 = head * 64;

  __shared__ alignas(16) short Klds[2][4096];
  __shared__ alignas(16) short Vlds[2][4096];
  __shared__ alignas(16) short Plds[4][2][16][72];

  short8 qf[2][2];
  int qrow[2];
#pragma unroll
  for (int qs = 0; qs < 2; ++qs) {
    qrow[qs] = n0 + w * 32 + qs * 16 + qc;
    qf[qs][0] = *reinterpret_cast<const short8*>(
        &Cm[(rowbase + qrow[qs]) * 1024 + qcol + lg * 8]);
    qf[qs][1] = *reinterpret_cast<const short8*>(
        &Cm[(rowbase + qrow[qs]) * 1024 + qcol + 32 + lg * 8]);
  }

  float l_run[2] = {0.f, 0.f};
  f32x4 o[2][4];
#pragma unroll
  for (int qs = 0; qs < 2; ++qs)
#pragma unroll
    for (int i = 0; i < 4; ++i) o[qs][i] = (f32x4){0.f, 0.f, 0.f, 0.f};
  const f32x4 minit = (f32x4){-M0F, -M0F, -M0F, -M0F};

  ASTAGE(0, 0);
  u64 mw0 = bits[(size_t)(n0 + w * 32 + qc) * 8];
  u64 mw1 = bits[(size_t)(n0 + w * 32 + 16 + qc) * 8];
  asm volatile("s_waitcnt vmcnt(0)" ::: "memory");
  __syncthreads();

  int cur = 0;
#pragma unroll 1
  for (int ch = 0; ch < 8; ++ch) {
    if (ch < 7) ASTAGE(cur ^ 1, ch + 1);            // prefetch next chunk
    u64 nmw0 = 0, nmw1 = 0;
    if (ch < 7) {                                    // prefetch next masks
      nmw0 = bits[(size_t)(n0 + w * 32 + qc) * 8 + ch + 1];
      nmw1 = bits[(size_t)(n0 + w * 32 + 16 + qc) * 8 + ch + 1];
    }
    // S^T = K . Q^T - 16 (scores pre-scaled by log2e/8 via q), exp2 fused
    float csum0 = 0.f, csum1 = 0.f;
#pragma unroll
    for (int s = 0; s < 4; ++s) {
      const int rk = s * 16 + qc;
      const short8 a0 = *reinterpret_cast<const short8*>(
          &Klds[cur][(rk * 8 + (lg ^ (rk & 7))) * 8]);
      const short8 a1 = *reinterpret_cast<const short8*>(
          &Klds[cur][(rk * 8 + ((4 + lg) ^ (rk & 7))) * 8]);
      f32x4 sa0 = minit, sa1 = minit;
      __builtin_amdgcn_s_setprio(1);
      sa0 = mfma16(a0, qf[0][0], sa0);
      sa0 = mfma16(a1, qf[0][1], sa0);
      sa1 = mfma16(a0, qf[1][0], sa1);
      sa1 = mfma16(a1, qf[1][1], sa1);
      __builtin_amdgcn_s_setprio(0);
      short4 p40, p41;
#pragma unroll
      for (int r = 0; r < 4; ++r) {
        const int kb = s * 16 + lg * 4 + r;
        const float pv0 = EXP2F(((mw0 >> kb) & 1ull) ? sa0[r] : -1e30f);
        const float pv1 = EXP2F(((mw1 >> kb) & 1ull) ? sa1[r] : -1e30f);
        csum0 += pv0; csum1 += pv1;
        ((short*)&p40)[r] = f2bf(pv0);
        ((short*)&p41)[r] = f2bf(pv1);
      }
      *reinterpret_cast<short4*>(&Plds[w][0][qc][s * 16 + lg * 4]) = p40;
      *reinterpret_cast<short4*>(&Plds[w][1][qc][s * 16 + lg * 4]) = p41;
    }
    csum0 += __shfl_xor(csum0, 16);
    csum0 += __shfl_xor(csum0, 32);
    csum1 += __shfl_xor(csum1, 16);
    csum1 += __shfl_xor(csum1, 32);
    l_run[0] += csum0;
    l_run[1] += csum1;

    // O^T += V^T . P^T, V fragments shared across q-subtiles
#pragma unroll
    for (int kh = 0; kh < 2; ++kh) {
      const short8 pb0 = *reinterpret_cast<const short8*>(
          &Plds[w][0][qc][kh * 32 + lg * 8]);
      const short8 pb1 = *reinterpret_cast<const short8*>(
          &Plds[w][1][qc][kh * 32 + lg * 8]);
      __builtin_amdgcn_s_setprio(1);
#pragma unroll
      for (int ds = 0; ds < 4; ++ds) {
        const int rd = ds * 16 + qc;
        const short8 va = *reinterpret_cast<const short8*>(
            &Vlds[cur][(rd * 8 + ((kh * 4 + lg) ^ (rd & 7))) * 8]);
        o[0][ds] = mfma16(va, pb0, o[0][ds]);
        o[1][ds] = mfma16(va, pb1, o[1][ds]);
      }
      __builtin_amdgcn_s_setprio(0);
    }
    asm volatile("s_waitcnt vmcnt(0)" ::: "memory");   // next chunk landed
    __syncthreads();                                    // all waves done with cur
    cur ^= 1;
    mw0 = nmw0; mw1 = nmw1;
  }
#pragma unroll
  for (int qs = 0; qs < 2; ++qs) {
    const float inv = l_run[qs] > 0.f ? 1.f / l_run[qs] : 0.f;
#pragma unroll
    for (int ds = 0; ds < 4; ++ds) {
      short4 t4;
      t4.x = f2bf(o[qs][ds][0] * inv);
      t4.y = f2bf(o[qs][ds][1] * inv);
      t4.z = f2bf(o[qs][ds][2] * inv);
      t4.w = f2bf(o[qs][ds][3] * inv);
      *reinterpret_cast<short4*>(
          &merged[(rowbase + qrow[qs]) * 512 + head * 64 + ds * 16 + lg * 4]) = t4;
    }
  }
}

// ---------------- launch ----------------
extern "C" void kernel_launch(void* const* d_in, const int* in_sizes, int n_in,
                              void* d_out, int out_size, void* d_ws, size_t ws_size,
                              hipStream_t stream) {
  const float* X        = (const float*)d_in[0];
  const float* STE      = (const float*)d_in[1];
  const int*   geo_mask = (const int*)d_in[2];
  const int*   sem_mask = (const int*)d_in[3];
  const float* PK       = (const float*)d_in[4];
  const float* Wq       = (const float*)d_in[5];
  const float* bq       = (const float*)d_in[6];
  const float* Wk       = (const float*)d_in[7];
  const float* bk       = (const float*)d_in[8];
  const float* Wv       = (const float*)d_in[9];
  const float* bv       = (const float*)d_in[10];
  const float* Wo       = (const float*)d_in[11];
  const float* bo       = (const float*)d_in[12];
  const float* Wsc      = (const float*)d_in[13];
  const float* Wwq      = (const float*)d_in[14];
  const float* Wpm      = (const float*)d_in[15];
  const float* Wpv      = (const float*)d_in[16];
  float* out = (float*)d_out;

  char* wsb = (char*)d_ws;
  short* Abf     = (short*)(wsb);                    // 24576x1024 bf16
  short* mergedb = (short*)(wsb);                    // aliases Abf (dead after QKV)
  short* Cm      = (short*)(wsb + 50331648);         // 24576x1024 bf16: q|k
  short* vT      = (short*)(wsb + 100663296);        // 512x24576 bf16
  short* Wt3     = (short*)(wsb + 125829120);        // 1536x1024 bf16
  short* Wot     = (short*)(wsb + 128974848);        // 512x512 bf16
  float* bqkv    = (float*)(wsb + 129499136);        // 1536 f32
  float* scalar  = (float*)(wsb + 129505280);        // 24576 f32
  float* mem     = (float*)(wsb + 129603584);
  float* val     = (float*)(wsb + 129619968);
  u64*   gbits   = (u64*)  (wsb + 129636352);
  u64*   sbits   = (u64*)  (wsb + 129669120);

  // all prep in one launch (cast+scalar | masks | tiled W transpose | bias | mem/val)
  prep_all<<<dim3(8662), dim3(256), 0, stream>>>(
      X, STE, geo_mask, sem_mask, PK, Wq, bq, Wk, bk, Wv, bv, Wo, Wsc, Wpm, Wpv,
      Abf, Wt3, Wot, bqkv, scalar, mem, val, gbits, sbits);

  // merged QKV GEMM: M=24576, K=1024, N=1536 (writes Cm q|k + vT transposed)
  gemm128<1, 12><<<dim3(2304), dim3(256), 0, stream>>>(
      Abf, 1024, Wt3, 1024, bqkv, Cm, vT, nullptr);

  // DFT branch adds into q channels [0,256)
  dft2<<<dim3(Mrows / 32), dim3(256), 0, stream>>>(scalar, Wwq, mem, val, Cm);

  // flash attention (fixed-reference softmax, no max pass)
  attn5<<<dim3(1536), dim3(256), 0, stream>>>(Cm, vT, gbits, sbits, mergedb);

  // output FC: M=24576, K=512, N=512, f32 out
  gemm128<0, 4><<<dim3(768), dim3(256), 0, stream>>>(
      mergedb, 512, Wot, 512, bo, nullptr, nullptr, out);
}